// Round 6
// baseline (884.886 us; speedup 1.0000x reference)
//
#include <hip/hip_runtime.h>
#include <cstddef>

// SlotAttention, 10 launches total.
//   xn = LN(x) bf16 once; k,v never materialized.
//   logits = (LN(slots)@Wqk + bqk) @ xn^T,  Wqk = SCALE*Wq^T@Wk  (q.bk const cancels in softmax)
//   gi     = (attn@xn) @ Wihv^T + bihv,     Wihv = W_ih@Wv, bihv = W_ih@bv + b_ih
//   (+1e-8 renorm dropped: perturbation ~2e-5 << threshold)
// Per iter: k_attnq (q-proj fused into attention) -> k_gigh (combine fused into gi GEMM, + gh GEMM)
//           -> k_gmlp (gates+LN_ff+W1+W2+residual fused, slot ping-pong buffers).

#define BB 64
#define NN 2048
#define DD 256
#define NCH 4
#define CHK 512
#define NITER 3

typedef unsigned short u16;
typedef unsigned int u32;

__device__ __forceinline__ float bflo(u32 u){ return __uint_as_float(u<<16); }
__device__ __forceinline__ float bfhi(u32 u){ return __uint_as_float(u & 0xffff0000u); }
__device__ __forceinline__ u16 f2bf(float f){
  u32 u = __float_as_uint(f);
  u32 r = u + 0x7fffu + ((u>>16)&1u);
  return (u16)(r>>16);
}

// ---- fused: LN(x)->bf16 (blocks 0..32767, 4 rows each) + slot init + weight folds ----
__global__ __launch_bounds__(256) void k_initln(const float* __restrict__ x, const float* __restrict__ g_in,
                                                const float* __restrict__ be_in, u16* __restrict__ xn,
                                                const float* __restrict__ noise, const float* __restrict__ mu,
                                                const float* __restrict__ sig, float* __restrict__ S,
                                                const float* __restrict__ Wq, const float* __restrict__ Wk,
                                                const float* __restrict__ bq, const float* __restrict__ Wih,
                                                const float* __restrict__ Wv, const float* __restrict__ bv,
                                                const float* __restrict__ bih,
                                                float* __restrict__ Wqk, float* __restrict__ bqk,
                                                float* __restrict__ Wihv, float* __restrict__ bihv){
  __shared__ float col[256];
  const int t = threadIdx.x;
  if(blockIdx.x < 32768){
    int wave = t>>6, lane = t&63;
    size_t row = (size_t)blockIdx.x*4 + wave;
    float4 v = *(const float4*)(x + row*256 + lane*4);
    float s1 = v.x+v.y+v.z+v.w;
    float s2 = v.x*v.x + v.y*v.y + v.z*v.z + v.w*v.w;
    #pragma unroll
    for(int off=1; off<64; off<<=1){ s1 += __shfl_xor(s1,off); s2 += __shfl_xor(s2,off); }
    float m = s1*(1.f/256.f);
    float var = s2*(1.f/256.f) - m*m;
    float rs = rsqrtf(var + 1e-5f);
    float4 gg = *(const float4*)(g_in + lane*4);
    float4 bb = *(const float4*)(be_in + lane*4);
    ushort4 o;
    o.x = f2bf((v.x-m)*rs*gg.x + bb.x);
    o.y = f2bf((v.y-m)*rs*gg.y + bb.y);
    o.z = f2bf((v.z-m)*rs*gg.z + bb.z);
    o.w = f2bf((v.w-m)*rs*gg.w + bb.w);
    *(ushort4*)(xn + row*256 + lane*4) = o;
    return;
  }
  int blk = blockIdx.x - 32768;
  if(blk < 512){
    int i = blk*256 + t;
    int d = i & 255;
    float sg = sig[d];
    float sp = fmaxf(sg, 0.f) + log1pf(expf(-fabsf(sg)));
    S[i] = mu[d] + sp * noise[i];
  } else if(blk < 768){
    int d1 = blk - 512;
    col[t] = Wq[t*256 + d1];
    __syncthreads();
    float acc = 0.f;
    #pragma unroll 4
    for(int j=0;j<256;j++) acc += col[j]*Wk[j*256+t];
    Wqk[d1*256+t] = acc * 0.0625f;
  } else if(blk < 1536){
    int c = blk - 768;
    col[t] = Wih[c*256+t];
    __syncthreads();
    float acc = 0.f;
    #pragma unroll 4
    for(int j=0;j<256;j++) acc += col[j]*Wv[j*256+t];
    Wihv[c*256+t] = acc;
  } else if(blk == 1536){
    float acc = 0.f;
    for(int j=0;j<256;j++) acc += bq[j]*Wk[j*256+t];
    bqk[t] = acc * 0.0625f;
  } else {
    for(int c=t;c<768;c+=256){
      float acc = 0.f;
      for(int j=0;j<256;j++) acc += Wih[c*256+j]*bv[j];
      bihv[c] = acc + bih[c];
    }
  }
}

// ---- attention with fused q-proj: grid (64 b, 4 chunks), 512 thr ----
__global__ __launch_bounds__(512) void k_attnq(const float* __restrict__ Sc, const float* __restrict__ g,
                                               const float* __restrict__ be, const float* __restrict__ Wqk,
                                               const float* __restrict__ bqk, const u16* __restrict__ xn,
                                               float* __restrict__ mP, float* __restrict__ lP,
                                               float* __restrict__ aP){
  __shared__ float qs[8][256];        // 8 KB : Q tile for this batch
  __shared__ float plT[8][512];       // 16 KB : P transposed [s][n]
  __shared__ float mS[8], lS[8];
  __shared__ union { float lnA[8][256]; float4 red[4][8][64]; } uu;  // 32 KB
  const int b = blockIdx.x, c = blockIdx.y, t = threadIdx.x;
  const int w = t>>6, l = t&63;

  // --- q-proj: wave w handles slot row w ---
  {
    float4 v = *(const float4*)(Sc + (size_t)(b*8+w)*256 + l*4);
    float s1 = v.x+v.y+v.z+v.w;
    float s2 = v.x*v.x+v.y*v.y+v.z*v.z+v.w*v.w;
    #pragma unroll
    for(int off=1; off<64; off<<=1){ s1 += __shfl_xor(s1,off); s2 += __shfl_xor(s2,off); }
    float m = s1*(1.f/256.f);
    float var = s2*(1.f/256.f) - m*m;
    float rs = rsqrtf(var + 1e-5f);
    float4 gg = *(const float4*)(g + l*4);
    float4 bb = *(const float4*)(be + l*4);
    float4 o;
    o.x=(v.x-m)*rs*gg.x+bb.x; o.y=(v.y-m)*rs*gg.y+bb.y;
    o.z=(v.z-m)*rs*gg.z+bb.z; o.w=(v.w-m)*rs*gg.w+bb.w;
    *(float4*)(&uu.lnA[w][l*4]) = o;
  }
  __syncthreads();
  {
    const int c4 = l*4;
    float4 acc = *(const float4*)(bqk + c4);
    #pragma unroll 2
    for(int d=0; d<256; d++){
      float a = uu.lnA[w][d];
      float4 wv = *(const float4*)(Wqk + (size_t)d*256 + c4);
      acc.x += a*wv.x; acc.y += a*wv.y; acc.z += a*wv.z; acc.w += a*wv.w;
    }
    *(float4*)(&qs[w][c4]) = acc;
  }
  __syncthreads();

  // --- logits: thread t owns n-row t of the 512-row chunk ---
  const uint4* xr = (const uint4*)(xn + ((size_t)(b*NN) + (size_t)c*CHK + t)*DD);
  float lg[8]={0,0,0,0,0,0,0,0};
  #pragma unroll 2
  for(int d8=0; d8<32; ++d8){
    uint4 u = xr[d8];
    float x0=bflo(u.x), x1=bfhi(u.x), x2=bflo(u.y), x3=bfhi(u.y);
    float x4=bflo(u.z), x5=bfhi(u.z), x6=bflo(u.w), x7=bfhi(u.w);
    #pragma unroll
    for(int s=0;s<8;s++){
      const float4* qrow = (const float4*)(&qs[s][d8*8]);
      float4 qa = qrow[0], qb = qrow[1];
      lg[s] += qa.x*x0 + qa.y*x1 + qa.z*x2 + qa.w*x3
             + qb.x*x4 + qb.y*x5 + qb.z*x6 + qb.w*x7;
    }
  }
  #pragma unroll
  for(int s=0;s<8;s++) plT[s][t] = lg[s];
  __syncthreads();
  {  // wave w reduces slot w max
    float mx = -1e30f;
    #pragma unroll
    for(int k=0;k<8;k++) mx = fmaxf(mx, plT[w][l + 64*k]);
    #pragma unroll
    for(int off=1; off<64; off<<=1) mx = fmaxf(mx, __shfl_xor(mx, off));
    if(l==0) mS[w] = mx;
  }
  __syncthreads();
  #pragma unroll
  for(int s=0;s<8;s++) plT[s][t] = __expf(lg[s] - mS[s]);
  __syncthreads();
  {  // wave w reduces slot w sum
    float sm = 0.f;
    #pragma unroll
    for(int k=0;k<8;k++) sm += plT[w][l + 64*k];
    #pragma unroll
    for(int off=1; off<64; off<<=1) sm += __shfl_xor(sm, off);
    if(l==0) lS[w] = sm;
  }
  __syncthreads();

  // --- acc = p @ xn : waves 0-3, wave w2 handles n = w2+4j ---
  if(w < 4){
    float4 acc4[8] = {};
    const u16* base = xn + ((size_t)(b*NN) + (size_t)c*CHK)*DD;
    #pragma unroll 4
    for(int j=0;j<128;++j){
      int nl = w + 4*j;
      uint2 u = *(const uint2*)(base + (size_t)nl*DD + l*4);
      float x0=bflo(u.x), x1=bfhi(u.x), x2=bflo(u.y), x3=bfhi(u.y);
      float p0=plT[0][nl], p1=plT[1][nl], p2=plT[2][nl], p3=plT[3][nl];
      float p4=plT[4][nl], p5=plT[5][nl], p6=plT[6][nl], p7=plT[7][nl];
      acc4[0].x += p0*x0; acc4[0].y += p0*x1; acc4[0].z += p0*x2; acc4[0].w += p0*x3;
      acc4[1].x += p1*x0; acc4[1].y += p1*x1; acc4[1].z += p1*x2; acc4[1].w += p1*x3;
      acc4[2].x += p2*x0; acc4[2].y += p2*x1; acc4[2].z += p2*x2; acc4[2].w += p2*x3;
      acc4[3].x += p3*x0; acc4[3].y += p3*x1; acc4[3].z += p3*x2; acc4[3].w += p3*x3;
      acc4[4].x += p4*x0; acc4[4].y += p4*x1; acc4[4].z += p4*x2; acc4[4].w += p4*x3;
      acc4[5].x += p5*x0; acc4[5].y += p5*x1; acc4[5].z += p5*x2; acc4[5].w += p5*x3;
      acc4[6].x += p6*x0; acc4[6].y += p6*x1; acc4[6].z += p6*x2; acc4[6].w += p6*x3;
      acc4[7].x += p7*x0; acc4[7].y += p7*x1; acc4[7].z += p7*x2; acc4[7].w += p7*x3;
    }
    #pragma unroll
    for(int s=0;s<8;s++) uu.red[w][s][l] = acc4[s];
  }
  __syncthreads();
  size_t pb = (size_t)(b*NCH + c)*8;
  {
    int s = t>>6, ll = t&63;
    float4 r0=uu.red[0][s][ll], r1=uu.red[1][s][ll], r2=uu.red[2][s][ll], r3=uu.red[3][s][ll];
    float4 o;
    o.x=r0.x+r1.x+r2.x+r3.x; o.y=r0.y+r1.y+r2.y+r3.y;
    o.z=r0.z+r1.z+r2.z+r3.z; o.w=r0.w+r1.w+r2.w+r3.w;
    *(float4*)(aP + pb*256 + s*256 + ll*4) = o;
  }
  if(t<8){ mP[pb+t] = mS[t]; lP[pb+t] = lS[t]; }
}

// ---- combine + gi/gh GEMM: grid (16 rowblk, 12 colblk, 2), 256 thr ----
__global__ __launch_bounds__(256) void k_gigh(const float* __restrict__ mP, const float* __restrict__ lP,
                                              const float* __restrict__ aP, const float* __restrict__ Wihv,
                                              const float* __restrict__ bihv, const float* __restrict__ Sc,
                                              const float* __restrict__ Whh, const float* __restrict__ bhh,
                                              float* __restrict__ Gi, float* __restrict__ Gh){
  __shared__ float Ut[32][260];
  __shared__ float wr[32][4];
  const int t = threadIdx.x;
  const int r0 = blockIdx.x*32, c0 = blockIdx.y*64, z = blockIdx.z;
  const float *Wm, *bi; float* Cm;
  if(z==0){
    if(t < 32){
      int r = r0 + t, b = r>>3, s = r&7;
      float M = -1e30f;
      #pragma unroll
      for(int c=0;c<NCH;c++) M = fmaxf(M, mP[(b*NCH+c)*8 + s]);
      float wc[NCH]; float L = 0.f;
      #pragma unroll
      for(int c=0;c<NCH;c++){ wc[c] = __expf(mP[(b*NCH+c)*8+s] - M); L += lP[(b*NCH+c)*8+s]*wc[c]; }
      float inv = 1.f/L;
      #pragma unroll
      for(int c=0;c<NCH;c++) wr[t][c] = wc[c]*inv;
    }
    __syncthreads();
    for(int e=t; e<32*256; e+=256){
      int i = e>>8, d = e&255;
      int r = r0+i, b = r>>3, s = r&7;
      size_t base = ((size_t)(b*NCH)*8 + s)*256 + d;
      Ut[i][d] = wr[i][0]*aP[base] + wr[i][1]*aP[base+2048]
               + wr[i][2]*aP[base+4096] + wr[i][3]*aP[base+6144];
    }
    __syncthreads();
    Wm = Wihv; bi = bihv; Cm = Gi;
  } else { Wm = Whh; bi = bhh; Cm = Gh; }
  const int ty = t>>4, tx = t&15;
  const int ri = ty*2, cj = c0 + tx*4;
  const float* w0 = Wm + (size_t)cj*256;
  float acc[2][4] = {};
  #pragma unroll 2
  for(int k=0;k<256;k+=4){
    float4 av[2];
    if(z==0){ av[0] = *(float4*)&Ut[ri][k]; av[1] = *(float4*)&Ut[ri+1][k]; }
    else {
      av[0] = *(const float4*)(Sc + (size_t)(r0+ri)*256 + k);
      av[1] = *(const float4*)(Sc + (size_t)(r0+ri+1)*256 + k);
    }
    float4 wv[4];
    #pragma unroll
    for(int j=0;j<4;j++) wv[j] = *(const float4*)(w0 + j*256 + k);
    #pragma unroll
    for(int i=0;i<2;i++)
      #pragma unroll
      for(int j=0;j<4;j++)
        acc[i][j] += av[i].x*wv[j].x + av[i].y*wv[j].y + av[i].z*wv[j].z + av[i].w*wv[j].w;
  }
  #pragma unroll
  for(int i=0;i<2;i++)
    #pragma unroll
    for(int j=0;j<4;j++)
      Cm[(size_t)(r0+ri+i)*768 + cj + j] = acc[i][j] + bi[cj+j];
}

// ---- gates + LN_ff + W1(relu) + W2 + residual: grid (32 rowblk, 8 colblk), 256 thr ----
__global__ __launch_bounds__(256) void k_gmlp(const float* __restrict__ Gi, const float* __restrict__ Gh,
                                              const float* __restrict__ Sc, const float* __restrict__ g_ff,
                                              const float* __restrict__ be_ff, const float* __restrict__ W1,
                                              const float* __restrict__ b1, const float* __restrict__ W2,
                                              const float* __restrict__ b2, float* __restrict__ outp){
  __shared__ float Sgt[16][260];
  __shared__ float Lnt[16][260];
  __shared__ float Ht[16][260];
  __shared__ float stat[16][2];
  const int t = threadIdx.x;
  const int r0 = blockIdx.x*16, c0 = blockIdx.y*32;
  // gates for rows r0..r0+15
  for(int e=t; e<16*256; e+=256){
    int i = e>>8, d = e&255;
    size_t r = r0+i;
    float ir = Gi[r*768 + d], iz = Gi[r*768 + 256 + d], inn = Gi[r*768 + 512 + d];
    float hr = Gh[r*768 + d], hz = Gh[r*768 + 256 + d], hn = Gh[r*768 + 512 + d];
    float rr = 1.f/(1.f + __expf(-(ir+hr)));
    float zz = 1.f/(1.f + __expf(-(iz+hz)));
    float nn = tanhf(inn + rr*hn);
    float prev = Sc[r*256 + d];
    Sgt[i][d] = (1.f-zz)*nn + zz*prev;
  }
  __syncthreads();
  // row stats: 16 rows x 16 lanes
  {
    int i = t>>4, k16 = t&15;
    float s1=0.f, s2=0.f;
    #pragma unroll
    for(int dd=0; dd<16; ++dd){ float v = Sgt[i][k16*16+dd]; s1 += v; s2 += v*v; }
    #pragma unroll
    for(int off=1; off<16; off<<=1){ s1 += __shfl_xor(s1,off); s2 += __shfl_xor(s2,off); }
    if(k16==0){
      float m = s1*(1.f/256.f);
      float var = s2*(1.f/256.f) - m*m;
      stat[i][0] = m; stat[i][1] = rsqrtf(var + 1e-5f);
    }
  }
  __syncthreads();
  for(int e=t; e<16*256; e+=256){
    int i = e>>8, d = e&255;
    Lnt[i][d] = (Sgt[i][d]-stat[i][0])*stat[i][1]*g_ff[d] + be_ff[d];
  }
  __syncthreads();
  // H = relu(Ln @ W1^T + b1): per loop-iter all threads on row i=k, col cc=t
  for(int e=t; e<16*256; e+=256){
    int i = e>>8, cc = e&255;
    const float* wrow = W1 + (size_t)cc*256;
    float acc = b1[cc];
    #pragma unroll 2
    for(int d=0; d<256; d+=4){
      float4 a = *(float4*)&Lnt[i][d];
      float4 wv = *(const float4*)(wrow + d);
      acc += a.x*wv.x + a.y*wv.y + a.z*wv.z + a.w*wv.w;
    }
    Ht[i][cc] = fmaxf(acc, 0.f);
  }
  __syncthreads();
  // out tile 16x32
  for(int e=t; e<16*32; e+=256){
    int i = e>>5, j = e&31;
    int cc = c0 + j;
    const float* wrow = W2 + (size_t)cc*256;
    float acc = b2[cc];
    #pragma unroll 2
    for(int d=0; d<256; d+=4){
      float4 h = *(float4*)&Ht[i][d];
      float4 wv = *(const float4*)(wrow + d);
      acc += h.x*wv.x + h.y*wv.y + h.z*wv.z + h.w*wv.w;
    }
    outp[(size_t)(r0+i)*256 + cc] = acc + Sgt[i][cc];
  }
}

extern "C" void kernel_launch(void* const* d_in, const int* in_sizes, int n_in,
                              void* d_out, int out_size, void* d_ws, size_t ws_size,
                              hipStream_t stream){
  const float* x    = (const float*)d_in[0];
  const float* noise= (const float*)d_in[1];
  const float* mu   = (const float*)d_in[2];
  const float* sig  = (const float*)d_in[3];
  const float* Wq   = (const float*)d_in[4];
  const float* bq   = (const float*)d_in[5];
  const float* Wk   = (const float*)d_in[6];
  // d_in[7] = bk : constant shift over n, cancels in softmax
  const float* Wv   = (const float*)d_in[8];
  const float* bv   = (const float*)d_in[9];
  const float* W_ih = (const float*)d_in[10];
  const float* b_ih = (const float*)d_in[11];
  const float* W_hh = (const float*)d_in[12];
  const float* b_hh = (const float*)d_in[13];
  const float* W1m  = (const float*)d_in[14];
  const float* b1v  = (const float*)d_in[15];
  const float* W2m  = (const float*)d_in[16];
  const float* b2v  = (const float*)d_in[17];
  const float* g_in = (const float*)d_in[18];
  const float* be_in= (const float*)d_in[19];
  const float* g_sl = (const float*)d_in[20];
  const float* be_sl= (const float*)d_in[21];
  const float* g_ff = (const float*)d_in[22];
  const float* be_ff= (const float*)d_in[23];

  char* p = (char*)d_ws;
  auto alloc = [&](size_t bytes)->char*{ char* q = p; p += (bytes + 255) & ~(size_t)255; return q; };
  u16*   xn   = (u16*)  alloc((size_t)BB*NN*DD*2);
  float* Wqk  = (float*)alloc(256*256*4);
  float* bqk  = (float*)alloc(256*4);
  float* Wihv = (float*)alloc(768*256*4);
  float* bihv = (float*)alloc(768*4);
  float* S0   = (float*)alloc(512*256*4);
  float* S1   = (float*)alloc(512*256*4);
  float* Gi   = (float*)alloc((size_t)512*768*4);
  float* Gh   = (float*)alloc((size_t)512*768*4);
  float* mP   = (float*)alloc(64*NCH*8*4);
  float* lP   = (float*)alloc(64*NCH*8*4);
  float* aP   = (float*)alloc((size_t)64*NCH*8*256*4);
  if((size_t)(p - (char*)d_ws) > ws_size) return;  // ws too small -> fail loudly

  k_initln<<<34306, 256, 0, stream>>>(x, g_in, be_in, xn, noise, mu, sig, S0,
                                      Wq, Wk, bq, W_ih, Wv, bv, b_ih, Wqk, bqk, Wihv, bihv);

  float* Sin = S0;
  float* Sping[2] = { S1, S0 };
  for(int it=0; it<NITER; ++it){
    float* Sout = (it==NITER-1) ? (float*)d_out : Sping[it&1];
    k_attnq<<<dim3(64, NCH), 512, 0, stream>>>(Sin, g_sl, be_sl, Wqk, bqk, xn, mP, lP, aP);
    k_gigh<<<dim3(16, 12, 2), 256, 0, stream>>>(mP, lP, aP, Wihv, bihv, Sin, W_hh, b_hh, Gi, Gh);
    k_gmlp<<<dim3(32, 8), 256, 0, stream>>>(Gi, Gh, Sin, g_ff, be_ff, W1m, b1v, W2m, b2v, Sout);
    Sin = Sout;
  }
}

// Round 7
// 509.038 us; speedup vs baseline: 1.7384x; 1.7384x over previous
//
#include <hip/hip_runtime.h>
#include <cstddef>

// SlotAttention, 10 launches.
//   xn = LN(x) bf16 once; k,v never materialized.
//   logits = (LN(slots)@Wqk + bqk) @ xn^T,  Wqk = SCALE*Wq^T@Wk  (q.bk const cancels in softmax)
//   gi     = (attn@xn) @ Wihv^T + bihv,     Wihv = W_ih@Wv, bihv = W_ih@bv + b_ih
//   (+1e-8 renorm dropped: perturbation ~2e-5 << threshold)
// Weights pre-transposed at init so all small GEMMs stream W coalesced (rank-1 update form).
// Per iter: k_attnq -> k_gg (combine+gi+gh+gates+LN_ff) -> k_mlp (W1+relu+W2+residual).

#define BB 64
#define NN 2048
#define DD 256
#define NCH 4
#define CHK 512
#define NITER 3

typedef unsigned short u16;
typedef unsigned int u32;

__device__ __forceinline__ float bflo(u32 u){ return __uint_as_float(u<<16); }
__device__ __forceinline__ float bfhi(u32 u){ return __uint_as_float(u & 0xffff0000u); }
__device__ __forceinline__ u16 f2bf(float f){
  u32 u = __float_as_uint(f);
  u32 r = u + 0x7fffu + ((u>>16)&1u);
  return (u16)(r>>16);
}

// ---- fused init: LN(x)->bf16, slot init, weight folds + transposes ----
__global__ __launch_bounds__(256) void k_initln(const float* __restrict__ x, const float* __restrict__ g_in,
                                                const float* __restrict__ be_in, u16* __restrict__ xn,
                                                const float* __restrict__ noise, const float* __restrict__ mu,
                                                const float* __restrict__ sig, float* __restrict__ S,
                                                const float* __restrict__ Wq, const float* __restrict__ Wk,
                                                const float* __restrict__ bq, const float* __restrict__ Wih,
                                                const float* __restrict__ Wv, const float* __restrict__ bv,
                                                const float* __restrict__ bih, const float* __restrict__ Whh,
                                                const float* __restrict__ W1, const float* __restrict__ W2,
                                                float* __restrict__ Wqk, float* __restrict__ bqk,
                                                float* __restrict__ WihvT, float* __restrict__ bihv,
                                                float* __restrict__ WhhT, float* __restrict__ W1T,
                                                float* __restrict__ W2T){
  __shared__ float col[256];
  const int t = threadIdx.x;
  if(blockIdx.x < 32768){
    int wave = t>>6, lane = t&63;
    size_t row = (size_t)blockIdx.x*4 + wave;
    float4 v = *(const float4*)(x + row*256 + lane*4);
    float s1 = v.x+v.y+v.z+v.w;
    float s2 = v.x*v.x + v.y*v.y + v.z*v.z + v.w*v.w;
    #pragma unroll
    for(int off=1; off<64; off<<=1){ s1 += __shfl_xor(s1,off); s2 += __shfl_xor(s2,off); }
    float m = s1*(1.f/256.f);
    float var = s2*(1.f/256.f) - m*m;
    float rs = rsqrtf(var + 1e-5f);
    float4 gg = *(const float4*)(g_in + lane*4);
    float4 bb = *(const float4*)(be_in + lane*4);
    ushort4 o;
    o.x = f2bf((v.x-m)*rs*gg.x + bb.x);
    o.y = f2bf((v.y-m)*rs*gg.y + bb.y);
    o.z = f2bf((v.z-m)*rs*gg.z + bb.z);
    o.w = f2bf((v.w-m)*rs*gg.w + bb.w);
    *(ushort4*)(xn + row*256 + lane*4) = o;
    return;
  }
  int blk = blockIdx.x - 32768;
  if(blk < 512){                       // slots = mu + softplus(sigma)*noise
    int i = blk*256 + t;
    int d = i & 255;
    float sg = sig[d];
    float sp = fmaxf(sg, 0.f) + log1pf(expf(-fabsf(sg)));
    S[i] = mu[d] + sp * noise[i];
  } else if(blk < 768){                // Wqk row d1 (kept [d][c]: attnq reads coalesced)
    int d1 = blk - 512;
    col[t] = Wq[t*256 + d1];
    __syncthreads();
    float acc = 0.f;
    #pragma unroll 4
    for(int j=0;j<256;j++) acc += col[j]*Wk[j*256+t];
    Wqk[d1*256+t] = acc * 0.0625f;
  } else if(blk < 1536){               // WihvT[d][c] = (W_ih@Wv)[c][d]
    int c = blk - 768;
    col[t] = Wih[c*256+t];
    __syncthreads();
    float acc = 0.f;
    #pragma unroll 4
    for(int j=0;j<256;j++) acc += col[j]*Wv[j*256+t];
    WihvT[(size_t)t*768 + c] = acc;
  } else if(blk < 2304){               // WhhT[d][c] = W_hh[c][d]
    int c = blk - 1536;
    WhhT[(size_t)t*768 + c] = Whh[(size_t)c*256 + t];
  } else if(blk < 2560){               // W1T
    int c = blk - 2304;
    W1T[(size_t)t*256 + c] = W1[(size_t)c*256 + t];
  } else if(blk < 2816){               // W2T
    int c = blk - 2560;
    W2T[(size_t)t*256 + c] = W2[(size_t)c*256 + t];
  } else if(blk == 2816){              // bqk
    float acc = 0.f;
    for(int j=0;j<256;j++) acc += bq[j]*Wk[j*256+t];
    bqk[t] = acc * 0.0625f;
  } else {                             // bihv
    for(int c=t;c<768;c+=256){
      float acc = 0.f;
      for(int j=0;j<256;j++) acc += Wih[c*256+j]*bv[j];
      bihv[c] = acc + bih[c];
    }
  }
}

// ---- attention with fused q-proj: grid (64 b, 4 chunks), 512 thr ----
__global__ __launch_bounds__(512) void k_attnq(const float* __restrict__ Sc, const float* __restrict__ g,
                                               const float* __restrict__ be, const float* __restrict__ Wqk,
                                               const float* __restrict__ bqk, const u16* __restrict__ xn,
                                               float* __restrict__ mP, float* __restrict__ lP,
                                               float* __restrict__ aP){
  __shared__ float qs[8][256];
  __shared__ float plT[8][512];
  __shared__ float mS[8], lS[8];
  __shared__ union { float lnA[8][256]; float4 red[4][8][64]; } uu;
  const int b = blockIdx.x, c = blockIdx.y, t = threadIdx.x;
  const int w = t>>6, l = t&63;

  // q-proj: wave w handles slot row w
  {
    float4 v = *(const float4*)(Sc + (size_t)(b*8+w)*256 + l*4);
    float s1 = v.x+v.y+v.z+v.w;
    float s2 = v.x*v.x+v.y*v.y+v.z*v.z+v.w*v.w;
    #pragma unroll
    for(int off=1; off<64; off<<=1){ s1 += __shfl_xor(s1,off); s2 += __shfl_xor(s2,off); }
    float m = s1*(1.f/256.f);
    float var = s2*(1.f/256.f) - m*m;
    float rs = rsqrtf(var + 1e-5f);
    float4 gg = *(const float4*)(g + l*4);
    float4 bb = *(const float4*)(be + l*4);
    float4 o;
    o.x=(v.x-m)*rs*gg.x+bb.x; o.y=(v.y-m)*rs*gg.y+bb.y;
    o.z=(v.z-m)*rs*gg.z+bb.z; o.w=(v.w-m)*rs*gg.w+bb.w;
    *(float4*)(&uu.lnA[w][l*4]) = o;
  }
  __syncthreads();
  {
    const int c4 = l*4;
    float4 acc = *(const float4*)(bqk + c4);
    #pragma unroll 2
    for(int d=0; d<256; d++){
      float a = uu.lnA[w][d];
      float4 wv = *(const float4*)(Wqk + (size_t)d*256 + c4);
      acc.x += a*wv.x; acc.y += a*wv.y; acc.z += a*wv.z; acc.w += a*wv.w;
    }
    *(float4*)(&qs[w][c4]) = acc;
  }
  __syncthreads();

  // logits: thread t owns n-row t of the 512-row chunk
  const uint4* xr = (const uint4*)(xn + ((size_t)(b*NN) + (size_t)c*CHK + t)*DD);
  float lg[8]={0,0,0,0,0,0,0,0};
  #pragma unroll 2
  for(int d8=0; d8<32; ++d8){
    uint4 u = xr[d8];
    float x0=bflo(u.x), x1=bfhi(u.x), x2=bflo(u.y), x3=bfhi(u.y);
    float x4=bflo(u.z), x5=bfhi(u.z), x6=bflo(u.w), x7=bfhi(u.w);
    #pragma unroll
    for(int s=0;s<8;s++){
      const float4* qrow = (const float4*)(&qs[s][d8*8]);
      float4 qa = qrow[0], qb = qrow[1];
      lg[s] += qa.x*x0 + qa.y*x1 + qa.z*x2 + qa.w*x3
             + qb.x*x4 + qb.y*x5 + qb.z*x6 + qb.w*x7;
    }
  }
  #pragma unroll
  for(int s=0;s<8;s++) plT[s][t] = lg[s];
  __syncthreads();
  {
    float mx = -1e30f;
    #pragma unroll
    for(int k=0;k<8;k++) mx = fmaxf(mx, plT[w][l + 64*k]);
    #pragma unroll
    for(int off=1; off<64; off<<=1) mx = fmaxf(mx, __shfl_xor(mx, off));
    if(l==0) mS[w] = mx;
  }
  __syncthreads();
  #pragma unroll
  for(int s=0;s<8;s++) plT[s][t] = __expf(lg[s] - mS[s]);
  __syncthreads();
  {
    float sm = 0.f;
    #pragma unroll
    for(int k=0;k<8;k++) sm += plT[w][l + 64*k];
    #pragma unroll
    for(int off=1; off<64; off<<=1) sm += __shfl_xor(sm, off);
    if(l==0) lS[w] = sm;
  }
  __syncthreads();

  // acc = p @ xn : waves 0-3 handle n = w+4j
  if(w < 4){
    float4 acc4[8] = {};
    const u16* base = xn + ((size_t)(b*NN) + (size_t)c*CHK)*DD;
    #pragma unroll 4
    for(int j=0;j<128;++j){
      int nl = w + 4*j;
      uint2 u = *(const uint2*)(base + (size_t)nl*DD + l*4);
      float x0=bflo(u.x), x1=bfhi(u.x), x2=bflo(u.y), x3=bfhi(u.y);
      float p0=plT[0][nl], p1=plT[1][nl], p2=plT[2][nl], p3=plT[3][nl];
      float p4=plT[4][nl], p5=plT[5][nl], p6=plT[6][nl], p7=plT[7][nl];
      acc4[0].x += p0*x0; acc4[0].y += p0*x1; acc4[0].z += p0*x2; acc4[0].w += p0*x3;
      acc4[1].x += p1*x0; acc4[1].y += p1*x1; acc4[1].z += p1*x2; acc4[1].w += p1*x3;
      acc4[2].x += p2*x0; acc4[2].y += p2*x1; acc4[2].z += p2*x2; acc4[2].w += p2*x3;
      acc4[3].x += p3*x0; acc4[3].y += p3*x1; acc4[3].z += p3*x2; acc4[3].w += p3*x3;
      acc4[4].x += p4*x0; acc4[4].y += p4*x1; acc4[4].z += p4*x2; acc4[4].w += p4*x3;
      acc4[5].x += p5*x0; acc4[5].y += p5*x1; acc4[5].z += p5*x2; acc4[5].w += p5*x3;
      acc4[6].x += p6*x0; acc4[6].y += p6*x1; acc4[6].z += p6*x2; acc4[6].w += p6*x3;
      acc4[7].x += p7*x0; acc4[7].y += p7*x1; acc4[7].z += p7*x2; acc4[7].w += p7*x3;
    }
    #pragma unroll
    for(int s=0;s<8;s++) uu.red[w][s][l] = acc4[s];
  }
  __syncthreads();
  size_t pb = (size_t)(b*NCH + c)*8;
  {
    int s = t>>6, ll = t&63;
    float4 r0=uu.red[0][s][ll], r1=uu.red[1][s][ll], r2=uu.red[2][s][ll], r3=uu.red[3][s][ll];
    float4 o;
    o.x=r0.x+r1.x+r2.x+r3.x; o.y=r0.y+r1.y+r2.y+r3.y;
    o.z=r0.z+r1.z+r2.z+r3.z; o.w=r0.w+r1.w+r2.w+r3.w;
    *(float4*)(aP + pb*256 + s*256 + ll*4) = o;
  }
  if(t<8){ mP[pb+t] = mS[t]; lP[pb+t] = lS[t]; }
}

// ---- combine + gi/gh GEMM + GRU gates + LN_ff: 256 blocks x 2 rows, 256 thr ----
__global__ __launch_bounds__(256) void k_gg(const float* __restrict__ mP, const float* __restrict__ lP,
                                            const float* __restrict__ aP, const float* __restrict__ WihvT,
                                            const float* __restrict__ bihv, const float* __restrict__ WhhT,
                                            const float* __restrict__ bhh, const float* __restrict__ Sc,
                                            const float* __restrict__ g_ff, const float* __restrict__ be_ff,
                                            float* __restrict__ Sg, float* __restrict__ Ln){
  __shared__ float Ut[2][256], Sp[2][256];
  __shared__ float red[2][2][4];
  const int t = threadIdx.x, w = t>>6, l = t&63;
  const int r0 = blockIdx.x*2;
  // combine -> Ut (normalized), stage prev slots
  #pragma unroll
  for(int i=0;i<2;i++){
    int r = r0+i, b = r>>3, s = r&7;
    const float* mpb = mP + b*32 + s;     // (b*NCH+c)*8+s, stride 8 per c
    const float* lpb = lP + b*32 + s;
    float M = -1e30f;
    #pragma unroll
    for(int c=0;c<NCH;c++) M = fmaxf(M, mpb[c*8]);
    float wc[NCH]; float L = 0.f;
    #pragma unroll
    for(int c=0;c<NCH;c++){ wc[c] = __expf(mpb[c*8] - M); L += lpb[c*8]*wc[c]; }
    float inv = 1.f/L;
    size_t base = ((size_t)(b*NCH)*8 + s)*256 + t;
    Ut[i][t] = (wc[0]*aP[base] + wc[1]*aP[base+2048] + wc[2]*aP[base+4096] + wc[3]*aP[base+6144])*inv;
    Sp[i][t] = Sc[(size_t)r*256 + t];
  }
  __syncthreads();
  // rank-1 GEMMs: thread t owns col t (r,z,n for gi and gh), rows r0,r0+1
  float b_ir = bihv[t], b_iz = bihv[256+t], b_in = bihv[512+t];
  float b_hr = bhh[t],  b_hz = bhh[256+t],  b_hn = bhh[512+t];
  float gir[2]={b_ir,b_ir}, giz[2]={b_iz,b_iz}, gin[2]={b_in,b_in};
  float ghr[2]={b_hr,b_hr}, ghz[2]={b_hz,b_hz}, ghn[2]={b_hn,b_hn};
  const float* wi = WihvT + t;
  const float* wh = WhhT + t;
  #pragma unroll 4
  for(int d=0; d<256; ++d){
    float wir = wi[(size_t)d*768], wiz = wi[(size_t)d*768+256], win = wi[(size_t)d*768+512];
    float whr = wh[(size_t)d*768], whz = wh[(size_t)d*768+256], whn = wh[(size_t)d*768+512];
    #pragma unroll
    for(int i=0;i<2;i++){
      float a = Ut[i][d], s = Sp[i][d];
      gir[i] += a*wir; giz[i] += a*wiz; gin[i] += a*win;
      ghr[i] += s*whr; ghz[i] += s*whz; ghn[i] += s*whn;
    }
  }
  // gates + LN_ff
  float sp[2];
  #pragma unroll
  for(int i=0;i<2;i++){
    float rr = 1.f/(1.f + __expf(-(gir[i]+ghr[i])));
    float zz = 1.f/(1.f + __expf(-(giz[i]+ghz[i])));
    float nn = tanhf(gin[i] + rr*ghn[i]);
    sp[i] = (1.f-zz)*nn + zz*Sp[i][t];
    float s1 = sp[i], s2 = sp[i]*sp[i];
    #pragma unroll
    for(int off=1; off<64; off<<=1){ s1 += __shfl_xor(s1,off); s2 += __shfl_xor(s2,off); }
    if(l==0){ red[i][0][w] = s1; red[i][1][w] = s2; }
  }
  __syncthreads();
  #pragma unroll
  for(int i=0;i<2;i++){
    float t1 = red[i][0][0]+red[i][0][1]+red[i][0][2]+red[i][0][3];
    float t2 = red[i][1][0]+red[i][1][1]+red[i][1][2]+red[i][1][3];
    float m = t1*(1.f/256.f);
    float var = t2*(1.f/256.f) - m*m;
    float rs = rsqrtf(var + 1e-5f);
    Sg[(size_t)(r0+i)*256 + t] = sp[i];
    Ln[(size_t)(r0+i)*256 + t] = (sp[i]-m)*rs*g_ff[t] + be_ff[t];
  }
}

// ---- MLP: W1(relu) + W2 + residual: 256 blocks x 2 rows, 256 thr ----
__global__ __launch_bounds__(256) void k_mlp(const float* __restrict__ Ln, const float* __restrict__ Sg,
                                             const float* __restrict__ W1T, const float* __restrict__ b1,
                                             const float* __restrict__ W2T, const float* __restrict__ b2,
                                             float* __restrict__ outp){
  __shared__ float Lt[2][256], Ht[2][256];
  const int t = threadIdx.x;
  const int r0 = blockIdx.x*2;
  Lt[0][t] = Ln[(size_t)r0*256 + t];
  Lt[1][t] = Ln[(size_t)(r0+1)*256 + t];
  __syncthreads();
  float h0 = b1[t], h1 = h0;
  const float* w1 = W1T + t;
  #pragma unroll 4
  for(int d=0; d<256; ++d){
    float wv = w1[(size_t)d*256];
    h0 += Lt[0][d]*wv; h1 += Lt[1][d]*wv;
  }
  Ht[0][t] = fmaxf(h0, 0.f);
  Ht[1][t] = fmaxf(h1, 0.f);
  __syncthreads();
  float o0 = b2[t], o1 = o0;
  const float* w2 = W2T + t;
  #pragma unroll 4
  for(int d=0; d<256; ++d){
    float wv = w2[(size_t)d*256];
    o0 += Ht[0][d]*wv; o1 += Ht[1][d]*wv;
  }
  outp[(size_t)r0*256 + t]     = o0 + Sg[(size_t)r0*256 + t];
  outp[(size_t)(r0+1)*256 + t] = o1 + Sg[(size_t)(r0+1)*256 + t];
}

extern "C" void kernel_launch(void* const* d_in, const int* in_sizes, int n_in,
                              void* d_out, int out_size, void* d_ws, size_t ws_size,
                              hipStream_t stream){
  const float* x    = (const float*)d_in[0];
  const float* noise= (const float*)d_in[1];
  const float* mu   = (const float*)d_in[2];
  const float* sig  = (const float*)d_in[3];
  const float* Wq   = (const float*)d_in[4];
  const float* bq   = (const float*)d_in[5];
  const float* Wk   = (const float*)d_in[6];
  // d_in[7] = bk : constant shift over n, cancels in softmax
  const float* Wv   = (const float*)d_in[8];
  const float* bv   = (const float*)d_in[9];
  const float* W_ih = (const float*)d_in[10];
  const float* b_ih = (const float*)d_in[11];
  const float* W_hh = (const float*)d_in[12];
  const float* b_hh = (const float*)d_in[13];
  const float* W1m  = (const float*)d_in[14];
  const float* b1v  = (const float*)d_in[15];
  const float* W2m  = (const float*)d_in[16];
  const float* b2v  = (const float*)d_in[17];
  const float* g_in = (const float*)d_in[18];
  const float* be_in= (const float*)d_in[19];
  const float* g_sl = (const float*)d_in[20];
  const float* be_sl= (const float*)d_in[21];
  const float* g_ff = (const float*)d_in[22];
  const float* be_ff= (const float*)d_in[23];

  char* p = (char*)d_ws;
  auto alloc = [&](size_t bytes)->char*{ char* q = p; p += (bytes + 255) & ~(size_t)255; return q; };
  u16*   xn    = (u16*)  alloc((size_t)BB*NN*DD*2);
  float* Wqk   = (float*)alloc(256*256*4);
  float* bqk   = (float*)alloc(256*4);
  float* WihvT = (float*)alloc((size_t)256*768*4);
  float* bihv  = (float*)alloc(768*4);
  float* WhhT  = (float*)alloc((size_t)256*768*4);
  float* W1T   = (float*)alloc(256*256*4);
  float* W2T   = (float*)alloc(256*256*4);
  float* S0    = (float*)alloc(512*256*4);
  float* S1    = (float*)alloc(512*256*4);
  float* Sg    = (float*)alloc(512*256*4);
  float* Ln    = (float*)alloc(512*256*4);
  float* mP    = (float*)alloc(64*NCH*8*4);
  float* lP    = (float*)alloc(64*NCH*8*4);
  float* aP    = (float*)alloc((size_t)64*NCH*8*256*4);
  if((size_t)(p - (char*)d_ws) > ws_size) return;  // fail loudly

  k_initln<<<35586, 256, 0, stream>>>(x, g_in, be_in, xn, noise, mu, sig, S0,
                                      Wq, Wk, bq, W_ih, Wv, bv, b_ih, W_hh, W1m, W2m,
                                      Wqk, bqk, WihvT, bihv, WhhT, W1T, W2T);

  float* Sin = S0;
  float* Sping[2] = { S1, S0 };
  for(int it=0; it<NITER; ++it){
    float* Sout = (it==NITER-1) ? (float*)d_out : Sping[it&1];
    k_attnq<<<dim3(64, NCH), 512, 0, stream>>>(Sin, g_sl, be_sl, Wqk, bqk, xn, mP, lP, aP);
    k_gg<<<256, 256, 0, stream>>>(mP, lP, aP, WihvT, bihv, WhhT, b_hh, Sin, g_ff, be_ff, Sg, Ln);
    k_mlp<<<256, 256, 0, stream>>>(Ln, Sg, W1T, b1v, W2T, b2v, Sout);
    Sin = Sout;
  }
}

// Round 8
// 415.452 us; speedup vs baseline: 2.1299x; 1.2253x over previous
//
#include <hip/hip_runtime.h>
#include <cstddef>

// SlotAttention, 8 launches.
//   xn = LN(x) bf16 once; k,v never materialized.
//   logits = (LN(slots)@Wqk + bqk) @ xn^T,  Wqk = SCALE*Wq^T@Wk  (q.bk const cancels in softmax)
//   gi     = (attn@xn) @ Wihv^T + bihv,     Wihv = W_ih@Wv, bihv = W_ih@bv + b_ih
//   (+1e-8 renorm dropped: perturbation ~2e-5 << threshold)
// kA: folds FIRST then LN(x) flood. kB: tiled transposes + iter0 q-proj.
// Per iter: k_attn (logits+softmax+partials) -> k_post (combine+GRU+LN_ff+MLP+residual+next q-proj).

#define BB 64
#define NN 2048
#define DD 256
#define NCH 8
#define CHK 256
#define NITER 3

typedef unsigned short u16;
typedef unsigned int u32;

__device__ __forceinline__ float bflo(u32 u){ return __uint_as_float(u<<16); }
__device__ __forceinline__ float bfhi(u32 u){ return __uint_as_float(u & 0xffff0000u); }
__device__ __forceinline__ u16 f2bf(float f){
  u32 u = __float_as_uint(f);
  u32 r = u + 0x7fffu + ((u>>16)&1u);
  return (u16)(r>>16);
}

// ---- kA: folds (first) + slots + biases + LN(x)->bf16 flood ----
__global__ __launch_bounds__(256) void kA(const float* __restrict__ x, const float* __restrict__ g_in,
                                          const float* __restrict__ be_in, u16* __restrict__ xn,
                                          const float* __restrict__ noise, const float* __restrict__ mu,
                                          const float* __restrict__ sig, float* __restrict__ S,
                                          const float* __restrict__ Wq, const float* __restrict__ Wk,
                                          const float* __restrict__ bq, const float* __restrict__ Wih,
                                          const float* __restrict__ Wv, const float* __restrict__ bv,
                                          const float* __restrict__ bih,
                                          float* __restrict__ Wqk, float* __restrict__ bqk,
                                          float* __restrict__ Wihv, float* __restrict__ bihv){
  __shared__ float col[256];
  const int t = threadIdx.x;
  const int blk = blockIdx.x;
  if(blk < 256){                        // Wqk row d1 = blk  (layout [d][c])
    col[t] = Wq[t*256 + blk];
    __syncthreads();
    float acc = 0.f;
    #pragma unroll 4
    for(int j=0;j<256;j++) acc += col[j]*Wk[j*256+t];
    Wqk[blk*256+t] = acc * 0.0625f;
  } else if(blk < 1024){                // Wihv row-major row c = blk-256
    int c = blk - 256;
    col[t] = Wih[c*256+t];
    __syncthreads();
    float acc = 0.f;
    #pragma unroll 4
    for(int j=0;j<256;j++) acc += col[j]*Wv[j*256+t];
    Wihv[(size_t)c*256+t] = acc;
  } else if(blk < 1536){                // slots
    int i = (blk-1024)*256 + t;
    float sg = sig[t];
    float sp = fmaxf(sg, 0.f) + log1pf(expf(-fabsf(sg)));
    S[i] = mu[t] + sp * noise[i];
  } else if(blk == 1536){               // bqk
    float acc = 0.f;
    for(int j=0;j<256;j++) acc += bq[j]*Wk[j*256+t];
    bqk[t] = acc * 0.0625f;
  } else if(blk == 1537){               // bihv
    for(int c=t;c<768;c+=256){
      float acc = 0.f;
      for(int j=0;j<256;j++) acc += Wih[c*256+j]*bv[j];
      bihv[c] = acc + bih[c];
    }
  } else {                              // LN(x) rows
    int wave = t>>6, lane = t&63;
    size_t row = (size_t)(blk-1538)*4 + wave;
    float4 v = *(const float4*)(x + row*256 + lane*4);
    float s1 = v.x+v.y+v.z+v.w;
    float s2 = v.x*v.x + v.y*v.y + v.z*v.z + v.w*v.w;
    #pragma unroll
    for(int off=1; off<64; off<<=1){ s1 += __shfl_xor(s1,off); s2 += __shfl_xor(s2,off); }
    float m = s1*(1.f/256.f);
    float var = s2*(1.f/256.f) - m*m;
    float rs = rsqrtf(var + 1e-5f);
    float4 gg = *(const float4*)(g_in + lane*4);
    float4 bb = *(const float4*)(be_in + lane*4);
    ushort4 o;
    o.x = f2bf((v.x-m)*rs*gg.x + bb.x);
    o.y = f2bf((v.y-m)*rs*gg.y + bb.y);
    o.z = f2bf((v.z-m)*rs*gg.z + bb.z);
    o.w = f2bf((v.w-m)*rs*gg.w + bb.w);
    *(ushort4*)(xn + row*256 + lane*4) = o;
  }
}

// ---- kB: LDS-tiled transposes (coalesced both sides) + iter0 q-proj ----
__global__ __launch_bounds__(256) void kB(const float* __restrict__ Wihv, const float* __restrict__ Whh,
                                          const float* __restrict__ W1, const float* __restrict__ W2,
                                          float* __restrict__ WihvT, float* __restrict__ WhhT,
                                          float* __restrict__ W1T, float* __restrict__ W2T,
                                          const float* __restrict__ S0, const float* __restrict__ g_sl,
                                          const float* __restrict__ be_sl, const float* __restrict__ Wqk,
                                          const float* __restrict__ bqk, float* __restrict__ Qq){
  __shared__ float tile[64][65];
  __shared__ float lnA[8][256];
  const int blk = blockIdx.x, t = threadIdx.x;
  if(blk < 128){
    const float* src; float* dst; int R, C, tb;
    if(blk < 48){ src=Wihv; dst=WihvT; R=768; C=256; tb=blk; }
    else if(blk < 96){ src=Whh; dst=WhhT; R=768; C=256; tb=blk-48; }
    else if(blk < 112){ src=W1; dst=W1T; R=256; C=256; tb=blk-96; }
    else { src=W2; dst=W2T; R=256; C=256; tb=blk-112; }
    const int tilesC = C/64;
    const int r0 = (tb/tilesC)*64, c0 = (tb%tilesC)*64;
    const int x = t&63, y = t>>6;
    #pragma unroll
    for(int k=0;k<16;k++) tile[y*16+k][x] = src[(size_t)(r0+y*16+k)*C + c0+x];
    __syncthreads();
    #pragma unroll
    for(int k=0;k<16;k++) dst[(size_t)(c0+y*16+k)*R + r0+x] = tile[x][y*16+k];
    return;
  }
  // iter-0 q-proj: batch bq8 = blk-128, rows bq8*8..+7
  const int w = t>>6, l = t&63;
  const int r0 = (blk-128)*8;
  #pragma unroll
  for(int rr=0; rr<2; rr++){
    int r = w*2 + rr;
    float4 v = *(const float4*)(S0 + (size_t)(r0+r)*256 + l*4);
    float s1 = v.x+v.y+v.z+v.w;
    float s2 = v.x*v.x+v.y*v.y+v.z*v.z+v.w*v.w;
    #pragma unroll
    for(int off=1; off<64; off<<=1){ s1 += __shfl_xor(s1,off); s2 += __shfl_xor(s2,off); }
    float m = s1*(1.f/256.f);
    float var = s2*(1.f/256.f) - m*m;
    float rs = rsqrtf(var + 1e-5f);
    float4 gg = *(const float4*)(g_sl + l*4);
    float4 bb = *(const float4*)(be_sl + l*4);
    float4 o;
    o.x=(v.x-m)*rs*gg.x+bb.x; o.y=(v.y-m)*rs*gg.y+bb.y;
    o.z=(v.z-m)*rs*gg.z+bb.z; o.w=(v.w-m)*rs*gg.w+bb.w;
    *(float4*)(&lnA[r][l*4]) = o;
  }
  __syncthreads();
  const int c4 = l*4;
  float acc[2][4] = {};
  #pragma unroll 2
  for(int k=0;k<256;k++){
    float4 wv = *(const float4*)(Wqk + (size_t)k*256 + c4);
    float a0 = lnA[2*w][k], a1 = lnA[2*w+1][k];
    acc[0][0]+=a0*wv.x; acc[0][1]+=a0*wv.y; acc[0][2]+=a0*wv.z; acc[0][3]+=a0*wv.w;
    acc[1][0]+=a1*wv.x; acc[1][1]+=a1*wv.y; acc[1][2]+=a1*wv.z; acc[1][3]+=a1*wv.w;
  }
  float4 bq4 = *(const float4*)(bqk + c4);
  #pragma unroll
  for(int rr=0; rr<2; rr++){
    float4 o;
    o.x=acc[rr][0]+bq4.x; o.y=acc[rr][1]+bq4.y; o.z=acc[rr][2]+bq4.z; o.w=acc[rr][3]+bq4.w;
    *(float4*)(Qq + (size_t)(r0+2*w+rr)*256 + c4) = o;
  }
}

// ---- attention partials: grid (64,8), 256 thr, chunk = 256 n-rows ----
__global__ __launch_bounds__(256) void k_attn(const float* __restrict__ Qq, const u16* __restrict__ xn,
                                              float* __restrict__ mP, float* __restrict__ lP,
                                              float* __restrict__ aP){
  __shared__ float qs[8][256];
  __shared__ float plT[8][256];
  __shared__ float mS[8], lS[8];
  __shared__ float4 red[4][8][64];
  const int b = blockIdx.x, c = blockIdx.y, t = threadIdx.x;
  const int w = t>>6, l = t&63;
  for(int i=t;i<2048;i+=256) ((float*)qs)[i] = Qq[b*2048 + i];
  __syncthreads();
  // logits: thread t owns n-row c*256+t
  const uint4* xr = (const uint4*)(xn + ((size_t)(b*NN) + (size_t)c*CHK + t)*DD);
  float lg[8]={0,0,0,0,0,0,0,0};
  #pragma unroll 2
  for(int d8=0; d8<32; ++d8){
    uint4 u = xr[d8];
    float x0=bflo(u.x), x1=bfhi(u.x), x2=bflo(u.y), x3=bfhi(u.y);
    float x4=bflo(u.z), x5=bfhi(u.z), x6=bflo(u.w), x7=bfhi(u.w);
    #pragma unroll
    for(int s=0;s<8;s++){
      const float4* qrow = (const float4*)(&qs[s][d8*8]);
      float4 qa = qrow[0], qb = qrow[1];
      lg[s] += qa.x*x0 + qa.y*x1 + qa.z*x2 + qa.w*x3
             + qb.x*x4 + qb.y*x5 + qb.z*x6 + qb.w*x7;
    }
  }
  #pragma unroll
  for(int s=0;s<8;s++) plT[s][t] = lg[s];
  __syncthreads();
  {  // per-s max: 32-lane group s = t>>5
    int s = t>>5, l32 = t&31;
    float mx = -1e30f;
    #pragma unroll
    for(int k=0;k<8;k++) mx = fmaxf(mx, plT[s][l32 + 32*k]);
    #pragma unroll
    for(int off=1; off<32; off<<=1) mx = fmaxf(mx, __shfl_xor(mx, off));
    if(l32==0) mS[s] = mx;
  }
  __syncthreads();
  #pragma unroll
  for(int s=0;s<8;s++) plT[s][t] = __expf(lg[s] - mS[s]);
  __syncthreads();
  {  // per-s sum
    int s = t>>5, l32 = t&31;
    float sm = 0.f;
    #pragma unroll
    for(int k=0;k<8;k++) sm += plT[s][l32 + 32*k];
    #pragma unroll
    for(int off=1; off<32; off<<=1) sm += __shfl_xor(sm, off);
    if(l32==0) lS[s] = sm;
  }
  __syncthreads();
  // acc = p @ xn : all 4 waves, wave w handles n = w+4j
  {
    float4 acc4[8] = {};
    const u16* base = xn + ((size_t)(b*NN) + (size_t)c*CHK)*DD;
    #pragma unroll 4
    for(int j=0;j<64;++j){
      int nl = w + 4*j;
      uint2 u = *(const uint2*)(base + (size_t)nl*DD + l*4);
      float x0=bflo(u.x), x1=bfhi(u.x), x2=bflo(u.y), x3=bfhi(u.y);
      float p0=plT[0][nl], p1=plT[1][nl], p2=plT[2][nl], p3=plT[3][nl];
      float p4=plT[4][nl], p5=plT[5][nl], p6=plT[6][nl], p7=plT[7][nl];
      acc4[0].x += p0*x0; acc4[0].y += p0*x1; acc4[0].z += p0*x2; acc4[0].w += p0*x3;
      acc4[1].x += p1*x0; acc4[1].y += p1*x1; acc4[1].z += p1*x2; acc4[1].w += p1*x3;
      acc4[2].x += p2*x0; acc4[2].y += p2*x1; acc4[2].z += p2*x2; acc4[2].w += p2*x3;
      acc4[3].x += p3*x0; acc4[3].y += p3*x1; acc4[3].z += p3*x2; acc4[3].w += p3*x3;
      acc4[4].x += p4*x0; acc4[4].y += p4*x1; acc4[4].z += p4*x2; acc4[4].w += p4*x3;
      acc4[5].x += p5*x0; acc4[5].y += p5*x1; acc4[5].z += p5*x2; acc4[5].w += p5*x3;
      acc4[6].x += p6*x0; acc4[6].y += p6*x1; acc4[6].z += p6*x2; acc4[6].w += p6*x3;
      acc4[7].x += p7*x0; acc4[7].y += p7*x1; acc4[7].z += p7*x2; acc4[7].w += p7*x3;
    }
    #pragma unroll
    for(int s=0;s<8;s++) red[w][s][l] = acc4[s];
  }
  __syncthreads();
  size_t pb = (size_t)(b*NCH + c)*8;
  for(int idx=t; idx<512; idx+=256){
    int s = idx>>6, ll = idx&63;
    float4 r0=red[0][s][ll], r1=red[1][s][ll], r2=red[2][s][ll], r3=red[3][s][ll];
    float4 o;
    o.x=r0.x+r1.x+r2.x+r3.x; o.y=r0.y+r1.y+r2.y+r3.y;
    o.z=r0.z+r1.z+r2.z+r3.z; o.w=r0.w+r1.w+r2.w+r3.w;
    *(float4*)(aP + pb*256 + s*256 + ll*4) = o;
  }
  if(t<8){ mP[pb+t] = mS[t]; lP[pb+t] = lS[t]; }
}

// ---- post: combine + gi/gh + GRU + LN_ff + W1 + W2 + residual (+ next q-proj) ----
// 256 blocks x 512 thr: thread = (row i = t>>8 of pair, col c = t&255)
__global__ __launch_bounds__(512) void k_post(const float* __restrict__ mP, const float* __restrict__ lP,
                                              const float* __restrict__ aP, const float* __restrict__ WihvT,
                                              const float* __restrict__ bihv, const float* __restrict__ WhhT,
                                              const float* __restrict__ bhh, const float* __restrict__ Sc,
                                              const float* __restrict__ g_ff, const float* __restrict__ be_ff,
                                              const float* __restrict__ W1T, const float* __restrict__ b1,
                                              const float* __restrict__ W2T, const float* __restrict__ b2,
                                              const float* __restrict__ g_sl, const float* __restrict__ be_sl,
                                              const float* __restrict__ Wqk, const float* __restrict__ bqk,
                                              float* __restrict__ Sout, float* __restrict__ Qq, int writeQ){
  __shared__ float Ut[2][256], Sp[2][256], Row[2][256], Ht[2][256];
  __shared__ float red[2][2][4];
  const int t = threadIdx.x;
  const int c = t&255, i = t>>8, w4 = (t>>6)&3, l = t&63;
  const int r = blockIdx.x*2 + i;
  const int b = r>>3, s = r&7;
  // combine (8 chunks)
  {
    const float* mpb = mP + b*64 + s;
    const float* lpb = lP + b*64 + s;
    float M = -1e30f;
    #pragma unroll
    for(int c8=0;c8<8;c8++) M = fmaxf(M, mpb[c8*8]);
    float wc[8]; float L = 0.f;
    #pragma unroll
    for(int c8=0;c8<8;c8++){ wc[c8] = __expf(mpb[c8*8] - M); L += lpb[c8*8]*wc[c8]; }
    float inv = 1.f/L;
    size_t base = ((size_t)b*64 + s)*256 + c;
    float u = 0.f;
    #pragma unroll
    for(int c8=0;c8<8;c8++) u += wc[c8]*aP[base + (size_t)c8*2048];
    Ut[i][c] = u*inv;
    Sp[i][c] = Sc[(size_t)r*256 + c];
  }
  __syncthreads();
  // gate GEMMs (coalesced WT streams)
  float gir = bihv[c], giz = bihv[256+c], gin = bihv[512+c];
  float ghr = bhh[c],  ghz = bhh[256+c],  ghn = bhh[512+c];
  {
    const float* wi = WihvT + c;
    const float* wh = WhhT + c;
    #pragma unroll 4
    for(int d=0; d<256; ++d){
      float a = Ut[i][d], sv = Sp[i][d];
      gir += a*wi[(size_t)d*768];      ghr += sv*wh[(size_t)d*768];
      giz += a*wi[(size_t)d*768+256];  ghz += sv*wh[(size_t)d*768+256];
      gin += a*wi[(size_t)d*768+512];  ghn += sv*wh[(size_t)d*768+512];
    }
  }
  float rr = 1.f/(1.f + __expf(-(gir+ghr)));
  float zz = 1.f/(1.f + __expf(-(giz+ghz)));
  float nn = tanhf(gin + rr*ghn);
  float sp = (1.f-zz)*nn + zz*Sp[i][c];
  // LN_ff stats (4 waves per row)
  {
    float s1 = sp, s2 = sp*sp;
    #pragma unroll
    for(int off=1; off<64; off<<=1){ s1 += __shfl_xor(s1,off); s2 += __shfl_xor(s2,off); }
    if(l==0){ red[i][0][w4] = s1; red[i][1][w4] = s2; }
  }
  __syncthreads();
  {
    float t1 = red[i][0][0]+red[i][0][1]+red[i][0][2]+red[i][0][3];
    float t2 = red[i][1][0]+red[i][1][1]+red[i][1][2]+red[i][1][3];
    float m = t1*(1.f/256.f);
    float var = t2*(1.f/256.f) - m*m;
    float rs = rsqrtf(var + 1e-5f);
    Row[i][c] = (sp-m)*rs*g_ff[c] + be_ff[c];
  }
  __syncthreads();
  // W1 + relu
  float h = b1[c];
  {
    const float* w1 = W1T + c;
    #pragma unroll 4
    for(int d=0; d<256; ++d) h += Row[i][d]*w1[(size_t)d*256];
  }
  Ht[i][c] = fmaxf(h, 0.f);
  __syncthreads();
  // W2 + residual
  float o = b2[c];
  {
    const float* w2 = W2T + c;
    #pragma unroll 4
    for(int d=0; d<256; ++d) o += Ht[i][d]*w2[(size_t)d*256];
  }
  float snew = o + sp;
  Sout[(size_t)r*256 + c] = snew;
  if(writeQ){
    __syncthreads();   // all W2 reads of Ht done
    {
      float s1 = snew, s2 = snew*snew;
      #pragma unroll
      for(int off=1; off<64; off<<=1){ s1 += __shfl_xor(s1,off); s2 += __shfl_xor(s2,off); }
      if(l==0){ red[i][0][w4] = s1; red[i][1][w4] = s2; }
    }
    __syncthreads();
    {
      float t1 = red[i][0][0]+red[i][0][1]+red[i][0][2]+red[i][0][3];
      float t2 = red[i][1][0]+red[i][1][1]+red[i][1][2]+red[i][1][3];
      float m = t1*(1.f/256.f);
      float var = t2*(1.f/256.f) - m*m;
      float rs = rsqrtf(var + 1e-5f);
      Ht[i][c] = (snew-m)*rs*g_sl[c] + be_sl[c];
    }
    __syncthreads();
    float q = bqk[c];
    const float* wq = Wqk + c;
    #pragma unroll 4
    for(int d=0; d<256; ++d) q += Ht[i][d]*wq[(size_t)d*256];
    Qq[(size_t)r*256 + c] = q;
  }
}

extern "C" void kernel_launch(void* const* d_in, const int* in_sizes, int n_in,
                              void* d_out, int out_size, void* d_ws, size_t ws_size,
                              hipStream_t stream){
  const float* x    = (const float*)d_in[0];
  const float* noise= (const float*)d_in[1];
  const float* mu   = (const float*)d_in[2];
  const float* sig  = (const float*)d_in[3];
  const float* Wq   = (const float*)d_in[4];
  const float* bq   = (const float*)d_in[5];
  const float* Wk   = (const float*)d_in[6];
  // d_in[7] = bk : constant shift over n, cancels in softmax
  const float* Wv   = (const float*)d_in[8];
  const float* bv   = (const float*)d_in[9];
  const float* W_ih = (const float*)d_in[10];
  const float* b_ih = (const float*)d_in[11];
  const float* W_hh = (const float*)d_in[12];
  const float* b_hh = (const float*)d_in[13];
  const float* W1m  = (const float*)d_in[14];
  const float* b1v  = (const float*)d_in[15];
  const float* W2m  = (const float*)d_in[16];
  const float* b2v  = (const float*)d_in[17];
  const float* g_in = (const float*)d_in[18];
  const float* be_in= (const float*)d_in[19];
  const float* g_sl = (const float*)d_in[20];
  const float* be_sl= (const float*)d_in[21];
  const float* g_ff = (const float*)d_in[22];
  const float* be_ff= (const float*)d_in[23];

  char* p = (char*)d_ws;
  auto alloc = [&](size_t bytes)->char*{ char* q = p; p += (bytes + 255) & ~(size_t)255; return q; };
  u16*   xn    = (u16*)  alloc((size_t)BB*NN*DD*2);
  float* Wqk   = (float*)alloc(256*256*4);
  float* bqk   = (float*)alloc(256*4);
  float* Wihv  = (float*)alloc((size_t)768*256*4);
  float* WihvT = (float*)alloc((size_t)256*768*4);
  float* bihv  = (float*)alloc(768*4);
  float* WhhT  = (float*)alloc((size_t)256*768*4);
  float* W1T   = (float*)alloc(256*256*4);
  float* W2T   = (float*)alloc(256*256*4);
  float* S0    = (float*)alloc(512*256*4);
  float* S1    = (float*)alloc(512*256*4);
  float* Qq    = (float*)alloc(512*256*4);
  float* mP    = (float*)alloc(64*NCH*8*4);
  float* lP    = (float*)alloc(64*NCH*8*4);
  float* aP    = (float*)alloc((size_t)64*NCH*8*256*4);
  if((size_t)(p - (char*)d_ws) > ws_size) return;  // fail loudly

  kA<<<34306, 256, 0, stream>>>(x, g_in, be_in, xn, noise, mu, sig, S0,
                                Wq, Wk, bq, W_ih, Wv, bv, b_ih, Wqk, bqk, Wihv, bihv);
  kB<<<192, 256, 0, stream>>>(Wihv, W_hh, W1m, W2m, WihvT, WhhT, W1T, W2T,
                              S0, g_sl, be_sl, Wqk, bqk, Qq);

  float* Sin = S0;
  float* Sping[2] = { S1, S0 };
  for(int it=0; it<NITER; ++it){
    float* Sout = (it==NITER-1) ? (float*)d_out : Sping[it&1];
    k_attn<<<dim3(64, NCH), 256, 0, stream>>>(Qq, xn, mP, lP, aP);
    k_post<<<256, 512, 0, stream>>>(mP, lP, aP, WihvT, bihv, WhhT, b_hh, Sin, g_ff, be_ff,
                                    W1T, b1v, W2T, b2v, g_sl, be_sl, Wqk, bqk,
                                    Sout, Qq, (it<NITER-1) ? 1 : 0);
    Sin = Sout;
  }
}

// Round 9
// 333.709 us; speedup vs baseline: 2.6517x; 1.2450x over previous
//
#include <hip/hip_runtime.h>
#include <cstddef>

// SlotAttention, 8 launches.
//   xn = LN(x) bf16 once; k,v never materialized.
//   logits = (LN(slots)@Wqk + bqk) @ xn^T,  Wqk = SCALE*Wq^T@Wk  (q.bk const cancels in softmax)
//   gi     = (attn@xn) @ Wihv^T + bihv,     Wihv = W_ih@Wv, bihv = W_ih@bv + b_ih
//   (+1e-8 renorm dropped: perturbation ~2e-5 << threshold)
// kA: folds FIRST then LN(x) flood. kB: tiled transposes + iter0 q-proj.
// Per iter: k_attn -> k_post (combine+GRU+LN_ff+MLP+residual+next q-proj), all weight
// streams vectorized (dwordx4 / dwordx2) to fix the R8 latency stall (VALUBusy 13%).

#define BB 64
#define NN 2048
#define DD 256
#define NCH 8
#define CHK 256
#define NITER 3

typedef unsigned short u16;
typedef unsigned int u32;

__device__ __forceinline__ float bflo(u32 u){ return __uint_as_float(u<<16); }
__device__ __forceinline__ float bfhi(u32 u){ return __uint_as_float(u & 0xffff0000u); }
__device__ __forceinline__ u16 f2bf(float f){
  u32 u = __float_as_uint(f);
  u32 r = u + 0x7fffu + ((u>>16)&1u);
  return (u16)(r>>16);
}

// ---- kA: folds (first) + slots + biases + LN(x)->bf16 flood ----
__global__ __launch_bounds__(256) void kA(const float* __restrict__ x, const float* __restrict__ g_in,
                                          const float* __restrict__ be_in, u16* __restrict__ xn,
                                          const float* __restrict__ noise, const float* __restrict__ mu,
                                          const float* __restrict__ sig, float* __restrict__ S,
                                          const float* __restrict__ Wq, const float* __restrict__ Wk,
                                          const float* __restrict__ bq, const float* __restrict__ Wih,
                                          const float* __restrict__ Wv, const float* __restrict__ bv,
                                          const float* __restrict__ bih,
                                          float* __restrict__ Wqk, float* __restrict__ bqk,
                                          float* __restrict__ Wihv, float* __restrict__ bihv){
  __shared__ float col[256];
  const int t = threadIdx.x;
  const int blk = blockIdx.x;
  if(blk < 256){                        // Wqk row d1 = blk  (layout [d][c])
    col[t] = Wq[t*256 + blk];
    __syncthreads();
    float acc = 0.f;
    #pragma unroll 4
    for(int j=0;j<256;j++) acc += col[j]*Wk[j*256+t];
    Wqk[blk*256+t] = acc * 0.0625f;
  } else if(blk < 1024){                // Wihv row-major row c = blk-256
    int c = blk - 256;
    col[t] = Wih[c*256+t];
    __syncthreads();
    float acc = 0.f;
    #pragma unroll 4
    for(int j=0;j<256;j++) acc += col[j]*Wv[j*256+t];
    Wihv[(size_t)c*256+t] = acc;
  } else if(blk < 1536){                // slots
    int i = (blk-1024)*256 + t;
    float sg = sig[t];
    float sp = fmaxf(sg, 0.f) + log1pf(expf(-fabsf(sg)));
    S[i] = mu[t] + sp * noise[i];
  } else if(blk == 1536){               // bqk
    float acc = 0.f;
    for(int j=0;j<256;j++) acc += bq[j]*Wk[j*256+t];
    bqk[t] = acc * 0.0625f;
  } else if(blk == 1537){               // bihv
    for(int c=t;c<768;c+=256){
      float acc = 0.f;
      for(int j=0;j<256;j++) acc += Wih[c*256+j]*bv[j];
      bihv[c] = acc + bih[c];
    }
  } else {                              // LN(x) rows
    int wave = t>>6, lane = t&63;
    size_t row = (size_t)(blk-1538)*4 + wave;
    float4 v = *(const float4*)(x + row*256 + lane*4);
    float s1 = v.x+v.y+v.z+v.w;
    float s2 = v.x*v.x + v.y*v.y + v.z*v.z + v.w*v.w;
    #pragma unroll
    for(int off=1; off<64; off<<=1){ s1 += __shfl_xor(s1,off); s2 += __shfl_xor(s2,off); }
    float m = s1*(1.f/256.f);
    float var = s2*(1.f/256.f) - m*m;
    float rs = rsqrtf(var + 1e-5f);
    float4 gg = *(const float4*)(g_in + lane*4);
    float4 bb = *(const float4*)(be_in + lane*4);
    ushort4 o;
    o.x = f2bf((v.x-m)*rs*gg.x + bb.x);
    o.y = f2bf((v.y-m)*rs*gg.y + bb.y);
    o.z = f2bf((v.z-m)*rs*gg.z + bb.z);
    o.w = f2bf((v.w-m)*rs*gg.w + bb.w);
    *(ushort4*)(xn + row*256 + lane*4) = o;
  }
}

// ---- kB: LDS-tiled transposes (coalesced both sides) + iter0 q-proj ----
__global__ __launch_bounds__(256) void kB(const float* __restrict__ Wihv, const float* __restrict__ Whh,
                                          const float* __restrict__ W1, const float* __restrict__ W2,
                                          float* __restrict__ WihvT, float* __restrict__ WhhT,
                                          float* __restrict__ W1T, float* __restrict__ W2T,
                                          const float* __restrict__ S0, const float* __restrict__ g_sl,
                                          const float* __restrict__ be_sl, const float* __restrict__ Wqk,
                                          const float* __restrict__ bqk, float* __restrict__ Qq){
  __shared__ float tile[64][65];
  __shared__ float lnA[8][256];
  const int blk = blockIdx.x, t = threadIdx.x;
  if(blk < 128){
    const float* src; float* dst; int R, C, tb;
    if(blk < 48){ src=Wihv; dst=WihvT; R=768; C=256; tb=blk; }
    else if(blk < 96){ src=Whh; dst=WhhT; R=768; C=256; tb=blk-48; }
    else if(blk < 112){ src=W1; dst=W1T; R=256; C=256; tb=blk-96; }
    else { src=W2; dst=W2T; R=256; C=256; tb=blk-112; }
    const int tilesC = C/64;
    const int r0 = (tb/tilesC)*64, c0 = (tb%tilesC)*64;
    const int x = t&63, y = t>>6;
    #pragma unroll
    for(int k=0;k<16;k++) tile[y*16+k][x] = src[(size_t)(r0+y*16+k)*C + c0+x];
    __syncthreads();
    #pragma unroll
    for(int k=0;k<16;k++) dst[(size_t)(c0+y*16+k)*R + r0+x] = tile[x][y*16+k];
    return;
  }
  // iter-0 q-proj: batch = blk-128, rows batch*8..+7
  const int w = t>>6, l = t&63;
  const int r0 = (blk-128)*8;
  #pragma unroll
  for(int rr=0; rr<2; rr++){
    int r = w*2 + rr;
    float4 v = *(const float4*)(S0 + (size_t)(r0+r)*256 + l*4);
    float s1 = v.x+v.y+v.z+v.w;
    float s2 = v.x*v.x+v.y*v.y+v.z*v.z+v.w*v.w;
    #pragma unroll
    for(int off=1; off<64; off<<=1){ s1 += __shfl_xor(s1,off); s2 += __shfl_xor(s2,off); }
    float m = s1*(1.f/256.f);
    float var = s2*(1.f/256.f) - m*m;
    float rs = rsqrtf(var + 1e-5f);
    float4 gg = *(const float4*)(g_sl + l*4);
    float4 bb = *(const float4*)(be_sl + l*4);
    float4 o;
    o.x=(v.x-m)*rs*gg.x+bb.x; o.y=(v.y-m)*rs*gg.y+bb.y;
    o.z=(v.z-m)*rs*gg.z+bb.z; o.w=(v.w-m)*rs*gg.w+bb.w;
    *(float4*)(&lnA[r][l*4]) = o;
  }
  __syncthreads();
  const int c4 = l*4;
  float acc[2][4] = {};
  #pragma unroll 2
  for(int k=0;k<256;k++){
    float4 wv = *(const float4*)(Wqk + (size_t)k*256 + c4);
    float a0 = lnA[2*w][k], a1 = lnA[2*w+1][k];
    acc[0][0]+=a0*wv.x; acc[0][1]+=a0*wv.y; acc[0][2]+=a0*wv.z; acc[0][3]+=a0*wv.w;
    acc[1][0]+=a1*wv.x; acc[1][1]+=a1*wv.y; acc[1][2]+=a1*wv.z; acc[1][3]+=a1*wv.w;
  }
  float4 bq4 = *(const float4*)(bqk + c4);
  #pragma unroll
  for(int rr=0; rr<2; rr++){
    float4 o;
    o.x=acc[rr][0]+bq4.x; o.y=acc[rr][1]+bq4.y; o.z=acc[rr][2]+bq4.z; o.w=acc[rr][3]+bq4.w;
    *(float4*)(Qq + (size_t)(r0+2*w+rr)*256 + c4) = o;
  }
}

// ---- attention partials: grid (64,8), 256 thr, chunk = 256 n-rows ----
__global__ __launch_bounds__(256) void k_attn(const float* __restrict__ Qq, const u16* __restrict__ xn,
                                              float* __restrict__ mP, float* __restrict__ lP,
                                              float* __restrict__ aP){
  __shared__ float qs[8][256];
  __shared__ float plT[8][256];
  __shared__ float mS[8], lS[8];
  __shared__ float4 red[4][8][64];
  const int b = blockIdx.x, c = blockIdx.y, t = threadIdx.x;
  const int w = t>>6, l = t&63;
  for(int i=t;i<2048;i+=256) ((float*)qs)[i] = Qq[b*2048 + i];
  __syncthreads();
  const uint4* xr = (const uint4*)(xn + ((size_t)(b*NN) + (size_t)c*CHK + t)*DD);
  float lg[8]={0,0,0,0,0,0,0,0};
  #pragma unroll 2
  for(int d8=0; d8<32; ++d8){
    uint4 u = xr[d8];
    float x0=bflo(u.x), x1=bfhi(u.x), x2=bflo(u.y), x3=bfhi(u.y);
    float x4=bflo(u.z), x5=bfhi(u.z), x6=bflo(u.w), x7=bfhi(u.w);
    #pragma unroll
    for(int s=0;s<8;s++){
      const float4* qrow = (const float4*)(&qs[s][d8*8]);
      float4 qa = qrow[0], qb = qrow[1];
      lg[s] += qa.x*x0 + qa.y*x1 + qa.z*x2 + qa.w*x3
             + qb.x*x4 + qb.y*x5 + qb.z*x6 + qb.w*x7;
    }
  }
  #pragma unroll
  for(int s=0;s<8;s++) plT[s][t] = lg[s];
  __syncthreads();
  {
    int s = t>>5, l32 = t&31;
    float mx = -1e30f;
    #pragma unroll
    for(int k=0;k<8;k++) mx = fmaxf(mx, plT[s][l32 + 32*k]);
    #pragma unroll
    for(int off=1; off<32; off<<=1) mx = fmaxf(mx, __shfl_xor(mx, off));
    if(l32==0) mS[s] = mx;
  }
  __syncthreads();
  #pragma unroll
  for(int s=0;s<8;s++) plT[s][t] = __expf(lg[s] - mS[s]);
  __syncthreads();
  {
    int s = t>>5, l32 = t&31;
    float sm = 0.f;
    #pragma unroll
    for(int k=0;k<8;k++) sm += plT[s][l32 + 32*k];
    #pragma unroll
    for(int off=1; off<32; off<<=1) sm += __shfl_xor(sm, off);
    if(l32==0) lS[s] = sm;
  }
  __syncthreads();
  {
    float4 acc4[8] = {};
    const u16* base = xn + ((size_t)(b*NN) + (size_t)c*CHK)*DD;
    #pragma unroll 4
    for(int j=0;j<64;++j){
      int nl = w + 4*j;
      uint2 u = *(const uint2*)(base + (size_t)nl*DD + l*4);
      float x0=bflo(u.x), x1=bfhi(u.x), x2=bflo(u.y), x3=bfhi(u.y);
      float p0=plT[0][nl], p1=plT[1][nl], p2=plT[2][nl], p3=plT[3][nl];
      float p4=plT[4][nl], p5=plT[5][nl], p6=plT[6][nl], p7=plT[7][nl];
      acc4[0].x += p0*x0; acc4[0].y += p0*x1; acc4[0].z += p0*x2; acc4[0].w += p0*x3;
      acc4[1].x += p1*x0; acc4[1].y += p1*x1; acc4[1].z += p1*x2; acc4[1].w += p1*x3;
      acc4[2].x += p2*x0; acc4[2].y += p2*x1; acc4[2].z += p2*x2; acc4[2].w += p2*x3;
      acc4[3].x += p3*x0; acc4[3].y += p3*x1; acc4[3].z += p3*x2; acc4[3].w += p3*x3;
      acc4[4].x += p4*x0; acc4[4].y += p4*x1; acc4[4].z += p4*x2; acc4[4].w += p4*x3;
      acc4[5].x += p5*x0; acc4[5].y += p5*x1; acc4[5].z += p5*x2; acc4[5].w += p5*x3;
      acc4[6].x += p6*x0; acc4[6].y += p6*x1; acc4[6].z += p6*x2; acc4[6].w += p6*x3;
      acc4[7].x += p7*x0; acc4[7].y += p7*x1; acc4[7].z += p7*x2; acc4[7].w += p7*x3;
    }
    #pragma unroll
    for(int s=0;s<8;s++) red[w][s][l] = acc4[s];
  }
  __syncthreads();
  size_t pb = (size_t)(b*NCH + c)*8;
  for(int idx=t; idx<512; idx+=256){
    int s = idx>>6, ll = idx&63;
    float4 r0=red[0][s][ll], r1=red[1][s][ll], r2=red[2][s][ll], r3=red[3][s][ll];
    float4 o;
    o.x=r0.x+r1.x+r2.x+r3.x; o.y=r0.y+r1.y+r2.y+r3.y;
    o.z=r0.z+r1.z+r2.z+r3.z; o.w=r0.w+r1.w+r2.w+r3.w;
    *(float4*)(aP + pb*256 + s*256 + ll*4) = o;
  }
  if(t<8){ mP[pb+t] = mS[t]; lP[pb+t] = lS[t]; }
}

// ---- post: combine + gi/gh + GRU + LN_ff + W1 + W2 + residual (+ next q-proj) ----
// 256 blocks x 512 thr; all weight streams vectorized.
__global__ __launch_bounds__(512) void k_post(const float* __restrict__ mP, const float* __restrict__ lP,
                                              const float* __restrict__ aP, const float* __restrict__ WihvT,
                                              const float* __restrict__ bihv, const float* __restrict__ WhhT,
                                              const float* __restrict__ bhh, const float* __restrict__ Sc,
                                              const float* __restrict__ g_ff, const float* __restrict__ be_ff,
                                              const float* __restrict__ W1T, const float* __restrict__ b1,
                                              const float* __restrict__ W2T, const float* __restrict__ b2,
                                              const float* __restrict__ g_sl, const float* __restrict__ be_sl,
                                              const float* __restrict__ Wqk, const float* __restrict__ bqk,
                                              float* __restrict__ Sout, float* __restrict__ Qq, int writeQ){
  __shared__ float Ut[2][256], Sp[2][256];
  __shared__ float Gt[2][2][768];
  __shared__ float Row[2][256], Ht[2][256], Snew[2][256], Lq[2][256];
  __shared__ float red[2][2][4];
  const int t = threadIdx.x;
  const int c = t&255, i = t>>8, w4 = (t>>6)&3, l = t&63;
  const int r = blockIdx.x*2 + i;
  const int b = r>>3, s = r&7;
  // combine (8 chunks) -> Ut, stage prev slots
  {
    const float* mpb = mP + b*64 + s;
    const float* lpb = lP + b*64 + s;
    float M = -1e30f;
    #pragma unroll
    for(int c8=0;c8<8;c8++) M = fmaxf(M, mpb[c8*8]);
    float wc[8]; float L = 0.f;
    #pragma unroll
    for(int c8=0;c8<8;c8++){ wc[c8] = __expf(mpb[c8*8] - M); L += lpb[c8*8]*wc[c8]; }
    float inv = 1.f/L;
    size_t base = ((size_t)b*64 + s)*256 + c;
    float u = 0.f;
    #pragma unroll
    for(int c8=0;c8<8;c8++) u += wc[c8]*aP[base + (size_t)c8*2048];
    Ut[i][c] = u*inv;
    Sp[i][c] = Sc[(size_t)r*256 + c];
  }
  __syncthreads();
  // gate GEMMs: 384 threads, (mat, col-quad), dwordx4 weight streams
  if(t < 384){
    const int mat = t/192, q4 = (t - mat*192)*4;
    const float* WT = mat ? WhhT : WihvT;
    const float* bb = mat ? bhh : bihv;
    const float* A0 = mat ? &Sp[0][0] : &Ut[0][0];
    const float* A1 = mat ? &Sp[1][0] : &Ut[1][0];
    float4 acc0 = *(const float4*)(bb + q4);
    float4 acc1 = acc0;
    const float* wp = WT + q4;
    #pragma unroll 8
    for(int d=0; d<256; ++d){
      float4 wv = *(const float4*)(wp + (size_t)d*768);
      float a0 = A0[d], a1 = A1[d];
      acc0.x += a0*wv.x; acc0.y += a0*wv.y; acc0.z += a0*wv.z; acc0.w += a0*wv.w;
      acc1.x += a1*wv.x; acc1.y += a1*wv.y; acc1.z += a1*wv.z; acc1.w += a1*wv.w;
    }
    *(float4*)(&Gt[mat][0][q4]) = acc0;
    *(float4*)(&Gt[mat][1][q4]) = acc1;
  }
  __syncthreads();
  // gates + LN_ff stats
  float sp;
  {
    float gir = Gt[0][i][c], giz = Gt[0][i][256+c], gin = Gt[0][i][512+c];
    float ghr = Gt[1][i][c], ghz = Gt[1][i][256+c], ghn = Gt[1][i][512+c];
    float rr = 1.f/(1.f + __expf(-(gir+ghr)));
    float zz = 1.f/(1.f + __expf(-(giz+ghz)));
    float nn = tanhf(gin + rr*ghn);
    sp = (1.f-zz)*nn + zz*Sp[i][c];
    float s1 = sp, s2 = sp*sp;
    #pragma unroll
    for(int off=1; off<64; off<<=1){ s1 += __shfl_xor(s1,off); s2 += __shfl_xor(s2,off); }
    if(l==0){ red[i][0][w4] = s1; red[i][1][w4] = s2; }
  }
  __syncthreads();
  {
    float t1 = red[i][0][0]+red[i][0][1]+red[i][0][2]+red[i][0][3];
    float t2 = red[i][1][0]+red[i][1][1]+red[i][1][2]+red[i][1][3];
    float m = t1*(1.f/256.f);
    float var = t2*(1.f/256.f) - m*m;
    float rs = rsqrtf(var + 1e-5f);
    Row[i][c] = (sp-m)*rs*g_ff[c] + be_ff[c];
    Ut[i][c] = sp;                    // keep sp for residual (Ut dead after gate GEMM)
  }
  __syncthreads();
  // W1 + relu: 256 threads, (row, col-pair), dwordx2 streams
  if(t < 256){
    const int i2 = t>>7, p2 = (t&127)*2;
    const float* w1 = W1T + p2;
    float2 acc = *(const float2*)(b1 + p2);
    #pragma unroll 8
    for(int d=0; d<256; ++d){
      float2 wv = *(const float2*)(w1 + (size_t)d*256);
      float a = Row[i2][d];
      acc.x += a*wv.x; acc.y += a*wv.y;
    }
    Ht[i2][p2]   = fmaxf(acc.x, 0.f);
    Ht[i2][p2+1] = fmaxf(acc.y, 0.f);
  }
  __syncthreads();
  // W2 + residual
  if(t < 256){
    const int i2 = t>>7, p2 = (t&127)*2;
    const float* w2 = W2T + p2;
    float2 acc = *(const float2*)(b2 + p2);
    #pragma unroll 8
    for(int d=0; d<256; ++d){
      float2 wv = *(const float2*)(w2 + (size_t)d*256);
      float a = Ht[i2][d];
      acc.x += a*wv.x; acc.y += a*wv.y;
    }
    float sn0 = acc.x + Ut[i2][p2];
    float sn1 = acc.y + Ut[i2][p2+1];
    const int rr2 = blockIdx.x*2 + i2;
    Sout[(size_t)rr2*256 + p2]   = sn0;
    Sout[(size_t)rr2*256 + p2+1] = sn1;
    Snew[i2][p2] = sn0; Snew[i2][p2+1] = sn1;
  }
  if(writeQ){
    __syncthreads();
    float sn = Snew[i][c];
    {
      float s1 = sn, s2 = sn*sn;
      #pragma unroll
      for(int off=1; off<64; off<<=1){ s1 += __shfl_xor(s1,off); s2 += __shfl_xor(s2,off); }
      if(l==0){ red[i][0][w4] = s1; red[i][1][w4] = s2; }
    }
    __syncthreads();
    {
      float t1 = red[i][0][0]+red[i][0][1]+red[i][0][2]+red[i][0][3];
      float t2 = red[i][1][0]+red[i][1][1]+red[i][1][2]+red[i][1][3];
      float m = t1*(1.f/256.f);
      float var = t2*(1.f/256.f) - m*m;
      float rs = rsqrtf(var + 1e-5f);
      Lq[i][c] = (sn-m)*rs*g_sl[c] + be_sl[c];
    }
    __syncthreads();
    if(t < 256){
      const int i2 = t>>7, p2 = (t&127)*2;
      const float* wq = Wqk + p2;
      float2 acc = *(const float2*)(bqk + p2);
      #pragma unroll 8
      for(int d=0; d<256; ++d){
        float2 wv = *(const float2*)(wq + (size_t)d*256);
        float a = Lq[i2][d];
        acc.x += a*wv.x; acc.y += a*wv.y;
      }
      const int rr2 = blockIdx.x*2 + i2;
      Qq[(size_t)rr2*256 + p2]   = acc.x;
      Qq[(size_t)rr2*256 + p2+1] = acc.y;
    }
  }
}

extern "C" void kernel_launch(void* const* d_in, const int* in_sizes, int n_in,
                              void* d_out, int out_size, void* d_ws, size_t ws_size,
                              hipStream_t stream){
  const float* x    = (const float*)d_in[0];
  const float* noise= (const float*)d_in[1];
  const float* mu   = (const float*)d_in[2];
  const float* sig  = (const float*)d_in[3];
  const float* Wq   = (const float*)d_in[4];
  const float* bq   = (const float*)d_in[5];
  const float* Wk   = (const float*)d_in[6];
  // d_in[7] = bk : constant shift over n, cancels in softmax
  const float* Wv   = (const float*)d_in[8];
  const float* bv   = (const float*)d_in[9];
  const float* W_ih = (const float*)d_in[10];
  const float* b_ih = (const float*)d_in[11];
  const float* W_hh = (const float*)d_in[12];
  const float* b_hh = (const float*)d_in[13];
  const float* W1m  = (const float*)d_in[14];
  const float* b1v  = (const float*)d_in[15];
  const float* W2m  = (const float*)d_in[16];
  const float* b2v  = (const float*)d_in[17];
  const float* g_in = (const float*)d_in[18];
  const float* be_in= (const float*)d_in[19];
  const float* g_sl = (const float*)d_in[20];
  const float* be_sl= (const float*)d_in[21];
  const float* g_ff = (const float*)d_in[22];
  const float* be_ff= (const float*)d_in[23];

  char* p = (char*)d_ws;
  auto alloc = [&](size_t bytes)->char*{ char* q = p; p += (bytes + 255) & ~(size_t)255; return q; };
  u16*   xn    = (u16*)  alloc((size_t)BB*NN*DD*2);
  float* Wqk   = (float*)alloc(256*256*4);
  float* bqk   = (float*)alloc(256*4);
  float* Wihv  = (float*)alloc((size_t)768*256*4);
  float* WihvT = (float*)alloc((size_t)256*768*4);
  float* bihv  = (float*)alloc(768*4);
  float* WhhT  = (float*)alloc((size_t)256*768*4);
  float* W1T   = (float*)alloc(256*256*4);
  float* W2T   = (float*)alloc(256*256*4);
  float* S0    = (float*)alloc(512*256*4);
  float* S1    = (float*)alloc(512*256*4);
  float* Qq    = (float*)alloc(512*256*4);
  float* mP    = (float*)alloc(64*NCH*8*4);
  float* lP    = (float*)alloc(64*NCH*8*4);
  float* aP    = (float*)alloc((size_t)64*NCH*8*256*4);
  if((size_t)(p - (char*)d_ws) > ws_size) return;  // fail loudly

  kA<<<34306, 256, 0, stream>>>(x, g_in, be_in, xn, noise, mu, sig, S0,
                                Wq, Wk, bq, W_ih, Wv, bv, b_ih, Wqk, bqk, Wihv, bihv);
  kB<<<192, 256, 0, stream>>>(Wihv, W_hh, W1m, W2m, WihvT, WhhT, W1T, W2T,
                              S0, g_sl, be_sl, Wqk, bqk, Qq);

  float* Sin = S0;
  float* Sping[2] = { S1, S0 };
  for(int it=0; it<NITER; ++it){
    float* Sout = (it==NITER-1) ? (float*)d_out : Sping[it&1];
    k_attn<<<dim3(64, NCH), 256, 0, stream>>>(Qq, xn, mP, lP, aP);
    k_post<<<256, 512, 0, stream>>>(mP, lP, aP, WihvT, bihv, WhhT, b_hh, Sin, g_ff, be_ff,
                                    W1T, b1v, W2T, b2v, g_sl, be_sl, Wqk, bqk,
                                    Sout, Qq, (it<NITER-1) ? 1 : 0);
    Sin = Sout;
  }
}

// Round 10
// 330.338 us; speedup vs baseline: 2.6787x; 1.0102x over previous
//
#include <hip/hip_runtime.h>
#include <cstddef>

// SlotAttention, 8 launches.
//   xn = LN(x) bf16 once; k,v never materialized.
//   logits = (LN(slots)@Wqk + bqk) @ xn^T,  Wqk = SCALE*Wq^T@Wk  (q.bk const cancels in softmax)
//   gi     = (attn@xn) @ Wihv^T + bihv,     Wihv = W_ih@Wv, bihv = W_ih@bv + b_ih
//   (+1e-8 renorm dropped: perturbation ~2e-5 << threshold)
// R10: occupancy doubling. k_attn slot-split z=2 (1024 blocks, 24KB LDS, 4 blk/CU);
//      k_post 1 row/block (512 blocks), W1/W2/Q d-split across all 512 threads.

#define BB 64
#define NN 2048
#define DD 256
#define NCH 8
#define CHK 256
#define NITER 3

typedef unsigned short u16;
typedef unsigned int u32;

__device__ __forceinline__ float bflo(u32 u){ return __uint_as_float(u<<16); }
__device__ __forceinline__ float bfhi(u32 u){ return __uint_as_float(u & 0xffff0000u); }
__device__ __forceinline__ u16 f2bf(float f){
  u32 u = __float_as_uint(f);
  u32 r = u + 0x7fffu + ((u>>16)&1u);
  return (u16)(r>>16);
}

// ---- kA: folds (first) + slots + biases + LN(x)->bf16 flood ----
__global__ __launch_bounds__(256) void kA(const float* __restrict__ x, const float* __restrict__ g_in,
                                          const float* __restrict__ be_in, u16* __restrict__ xn,
                                          const float* __restrict__ noise, const float* __restrict__ mu,
                                          const float* __restrict__ sig, float* __restrict__ S,
                                          const float* __restrict__ Wq, const float* __restrict__ Wk,
                                          const float* __restrict__ bq, const float* __restrict__ Wih,
                                          const float* __restrict__ Wv, const float* __restrict__ bv,
                                          const float* __restrict__ bih,
                                          float* __restrict__ Wqk, float* __restrict__ bqk,
                                          float* __restrict__ Wihv, float* __restrict__ bihv){
  __shared__ float col[256];
  const int t = threadIdx.x;
  const int blk = blockIdx.x;
  if(blk < 256){                        // Wqk row d1 = blk  (layout [d][c])
    col[t] = Wq[t*256 + blk];
    __syncthreads();
    float acc = 0.f;
    #pragma unroll 4
    for(int j=0;j<256;j++) acc += col[j]*Wk[j*256+t];
    Wqk[blk*256+t] = acc * 0.0625f;
  } else if(blk < 1024){                // Wihv row-major row c = blk-256
    int c = blk - 256;
    col[t] = Wih[c*256+t];
    __syncthreads();
    float acc = 0.f;
    #pragma unroll 4
    for(int j=0;j<256;j++) acc += col[j]*Wv[j*256+t];
    Wihv[(size_t)c*256+t] = acc;
  } else if(blk < 1536){                // slots
    int i = (blk-1024)*256 + t;
    float sg = sig[t];
    float sp = fmaxf(sg, 0.f) + log1pf(expf(-fabsf(sg)));
    S[i] = mu[t] + sp * noise[i];
  } else if(blk == 1536){               // bqk
    float acc = 0.f;
    for(int j=0;j<256;j++) acc += bq[j]*Wk[j*256+t];
    bqk[t] = acc * 0.0625f;
  } else if(blk == 1537){               // bihv
    for(int c=t;c<768;c+=256){
      float acc = 0.f;
      for(int j=0;j<256;j++) acc += Wih[c*256+j]*bv[j];
      bihv[c] = acc + bih[c];
    }
  } else {                              // LN(x) rows
    int wave = t>>6, lane = t&63;
    size_t row = (size_t)(blk-1538)*4 + wave;
    float4 v = *(const float4*)(x + row*256 + lane*4);
    float s1 = v.x+v.y+v.z+v.w;
    float s2 = v.x*v.x + v.y*v.y + v.z*v.z + v.w*v.w;
    #pragma unroll
    for(int off=1; off<64; off<<=1){ s1 += __shfl_xor(s1,off); s2 += __shfl_xor(s2,off); }
    float m = s1*(1.f/256.f);
    float var = s2*(1.f/256.f) - m*m;
    float rs = rsqrtf(var + 1e-5f);
    float4 gg = *(const float4*)(g_in + lane*4);
    float4 bb = *(const float4*)(be_in + lane*4);
    ushort4 o;
    o.x = f2bf((v.x-m)*rs*gg.x + bb.x);
    o.y = f2bf((v.y-m)*rs*gg.y + bb.y);
    o.z = f2bf((v.z-m)*rs*gg.z + bb.z);
    o.w = f2bf((v.w-m)*rs*gg.w + bb.w);
    *(ushort4*)(xn + row*256 + lane*4) = o;
  }
}

// ---- kB: LDS-tiled transposes (coalesced both sides) + iter0 q-proj ----
__global__ __launch_bounds__(256) void kB(const float* __restrict__ Wihv, const float* __restrict__ Whh,
                                          const float* __restrict__ W1, const float* __restrict__ W2,
                                          float* __restrict__ WihvT, float* __restrict__ WhhT,
                                          float* __restrict__ W1T, float* __restrict__ W2T,
                                          const float* __restrict__ S0, const float* __restrict__ g_sl,
                                          const float* __restrict__ be_sl, const float* __restrict__ Wqk,
                                          const float* __restrict__ bqk, float* __restrict__ Qq){
  __shared__ float tile[64][65];
  __shared__ float lnA[8][256];
  const int blk = blockIdx.x, t = threadIdx.x;
  if(blk < 128){
    const float* src; float* dst; int R, C, tb;
    if(blk < 48){ src=Wihv; dst=WihvT; R=768; C=256; tb=blk; }
    else if(blk < 96){ src=Whh; dst=WhhT; R=768; C=256; tb=blk-48; }
    else if(blk < 112){ src=W1; dst=W1T; R=256; C=256; tb=blk-96; }
    else { src=W2; dst=W2T; R=256; C=256; tb=blk-112; }
    const int tilesC = C/64;
    const int r0 = (tb/tilesC)*64, c0 = (tb%tilesC)*64;
    const int x = t&63, y = t>>6;
    #pragma unroll
    for(int k=0;k<16;k++) tile[y*16+k][x] = src[(size_t)(r0+y*16+k)*C + c0+x];
    __syncthreads();
    #pragma unroll
    for(int k=0;k<16;k++) dst[(size_t)(c0+y*16+k)*R + r0+x] = tile[x][y*16+k];
    return;
  }
  // iter-0 q-proj: batch = blk-128, rows batch*8..+7
  const int w = t>>6, l = t&63;
  const int r0 = (blk-128)*8;
  #pragma unroll
  for(int rr=0; rr<2; rr++){
    int r = w*2 + rr;
    float4 v = *(const float4*)(S0 + (size_t)(r0+r)*256 + l*4);
    float s1 = v.x+v.y+v.z+v.w;
    float s2 = v.x*v.x+v.y*v.y+v.z*v.z+v.w*v.w;
    #pragma unroll
    for(int off=1; off<64; off<<=1){ s1 += __shfl_xor(s1,off); s2 += __shfl_xor(s2,off); }
    float m = s1*(1.f/256.f);
    float var = s2*(1.f/256.f) - m*m;
    float rs = rsqrtf(var + 1e-5f);
    float4 gg = *(const float4*)(g_sl + l*4);
    float4 bb = *(const float4*)(be_sl + l*4);
    float4 o;
    o.x=(v.x-m)*rs*gg.x+bb.x; o.y=(v.y-m)*rs*gg.y+bb.y;
    o.z=(v.z-m)*rs*gg.z+bb.z; o.w=(v.w-m)*rs*gg.w+bb.w;
    *(float4*)(&lnA[r][l*4]) = o;
  }
  __syncthreads();
  const int c4 = l*4;
  float acc[2][4] = {};
  #pragma unroll 2
  for(int k=0;k<256;k++){
    float4 wv = *(const float4*)(Wqk + (size_t)k*256 + c4);
    float a0 = lnA[2*w][k], a1 = lnA[2*w+1][k];
    acc[0][0]+=a0*wv.x; acc[0][1]+=a0*wv.y; acc[0][2]+=a0*wv.z; acc[0][3]+=a0*wv.w;
    acc[1][0]+=a1*wv.x; acc[1][1]+=a1*wv.y; acc[1][2]+=a1*wv.z; acc[1][3]+=a1*wv.w;
  }
  float4 bq4 = *(const float4*)(bqk + c4);
  #pragma unroll
  for(int rr=0; rr<2; rr++){
    float4 o;
    o.x=acc[rr][0]+bq4.x; o.y=acc[rr][1]+bq4.y; o.z=acc[rr][2]+bq4.z; o.w=acc[rr][3]+bq4.w;
    *(float4*)(Qq + (size_t)(r0+2*w+rr)*256 + c4) = o;
  }
}

// ---- attention partials: grid (64, 8, 2), 256 thr, 4 slots per block ----
__global__ __launch_bounds__(256) void k_attn(const float* __restrict__ Qq, const u16* __restrict__ xn,
                                              float* __restrict__ mP, float* __restrict__ lP,
                                              float* __restrict__ aP){
  __shared__ float qs[4][256];       // 4 KB
  __shared__ float plT[4][256];      // 4 KB
  __shared__ float mS[4], lS[4];
  __shared__ float4 red[4][4][64];   // 16 KB
  const int b = blockIdx.x, c = blockIdx.y, z = blockIdx.z, t = threadIdx.x;
  const int w = t>>6, l = t&63;
  for(int i=t;i<1024;i+=256) ((float*)qs)[i] = Qq[b*2048 + z*1024 + i];
  __syncthreads();
  // logits: thread t owns n-row c*256+t, 4 slots
  const uint4* xr = (const uint4*)(xn + ((size_t)(b*NN) + (size_t)c*CHK + t)*DD);
  float lg[4]={0,0,0,0};
  #pragma unroll 4
  for(int d8=0; d8<32; ++d8){
    uint4 u = xr[d8];
    float x0=bflo(u.x), x1=bfhi(u.x), x2=bflo(u.y), x3=bfhi(u.y);
    float x4=bflo(u.z), x5=bfhi(u.z), x6=bflo(u.w), x7=bfhi(u.w);
    #pragma unroll
    for(int s=0;s<4;s++){
      const float4* qrow = (const float4*)(&qs[s][d8*8]);
      float4 qa = qrow[0], qb = qrow[1];
      lg[s] += qa.x*x0 + qa.y*x1 + qa.z*x2 + qa.w*x3
             + qb.x*x4 + qb.y*x5 + qb.z*x6 + qb.w*x7;
    }
  }
  #pragma unroll
  for(int s=0;s<4;s++) plT[s][t] = lg[s];
  __syncthreads();
  // wave w reduces slot w (max: order-free)
  {
    float mx = -1e30f;
    #pragma unroll
    for(int k=0;k<4;k++) mx = fmaxf(mx, plT[w][l + 64*k]);
    #pragma unroll
    for(int off=1; off<64; off<<=1) mx = fmaxf(mx, __shfl_xor(mx, off));
    if(l==0) mS[w] = mx;
  }
  __syncthreads();
  #pragma unroll
  for(int s=0;s<4;s++) plT[s][t] = __expf(lg[s] - mS[s]);
  __syncthreads();
  {
    float sm = 0.f;
    #pragma unroll
    for(int k=0;k<4;k++) sm += plT[w][l + 64*k];
    #pragma unroll
    for(int off=1; off<64; off<<=1) sm += __shfl_xor(sm, off);
    if(l==0) lS[w] = sm;
  }
  __syncthreads();
  // acc = p @ xn : wave w handles n = w+4j
  {
    float4 acc4[4] = {};
    const u16* base = xn + ((size_t)(b*NN) + (size_t)c*CHK)*DD;
    #pragma unroll 8
    for(int j=0;j<64;++j){
      int nl = w + 4*j;
      uint2 u = *(const uint2*)(base + (size_t)nl*DD + l*4);
      float x0=bflo(u.x), x1=bfhi(u.x), x2=bflo(u.y), x3=bfhi(u.y);
      float p0=plT[0][nl], p1=plT[1][nl], p2=plT[2][nl], p3=plT[3][nl];
      acc4[0].x += p0*x0; acc4[0].y += p0*x1; acc4[0].z += p0*x2; acc4[0].w += p0*x3;
      acc4[1].x += p1*x0; acc4[1].y += p1*x1; acc4[1].z += p1*x2; acc4[1].w += p1*x3;
      acc4[2].x += p2*x0; acc4[2].y += p2*x1; acc4[2].z += p2*x2; acc4[2].w += p2*x3;
      acc4[3].x += p3*x0; acc4[3].y += p3*x1; acc4[3].z += p3*x2; acc4[3].w += p3*x3;
    }
    #pragma unroll
    for(int s=0;s<4;s++) red[w][s][l] = acc4[s];
  }
  __syncthreads();
  const size_t pb = (size_t)(b*NCH + c)*8 + z*4;   // global slot base
  {
    int s = t>>6, ll = t&63;   // 4 slots x 64 lanes = 256 = blockDim
    float4 r0=red[0][s][ll], r1=red[1][s][ll], r2=red[2][s][ll], r3=red[3][s][ll];
    float4 o;
    o.x=r0.x+r1.x+r2.x+r3.x; o.y=r0.y+r1.y+r2.y+r3.y;
    o.z=r0.z+r1.z+r2.z+r3.z; o.w=r0.w+r1.w+r2.w+r3.w;
    *(float4*)(aP + (pb + s)*256 + ll*4) = o;
  }
  if(t<4){ mP[pb+t] = mS[t]; lP[pb+t] = lS[t]; }
}

// ---- post: combine + gi/gh + GRU + LN_ff + W1 + W2 + residual (+ next q-proj) ----
// 512 blocks x 512 thr, ONE slot-row per block; W1/W2/Q split d across thread halves.
__global__ __launch_bounds__(512) void k_post(const float* __restrict__ mP, const float* __restrict__ lP,
                                              const float* __restrict__ aP, const float* __restrict__ WihvT,
                                              const float* __restrict__ bihv, const float* __restrict__ WhhT,
                                              const float* __restrict__ bhh, const float* __restrict__ Sc,
                                              const float* __restrict__ g_ff, const float* __restrict__ be_ff,
                                              const float* __restrict__ W1T, const float* __restrict__ b1,
                                              const float* __restrict__ W2T, const float* __restrict__ b2,
                                              const float* __restrict__ g_sl, const float* __restrict__ be_sl,
                                              const float* __restrict__ Wqk, const float* __restrict__ bqk,
                                              float* __restrict__ Sout, float* __restrict__ Qq, int writeQ){
  __shared__ float Ut[256], Sp[256], Gt[2][768];
  __shared__ float Row[256], Ht[256], Snew[256], Lq[256], Hp[2][256];
  __shared__ float red2[2][4];
  const int t = threadIdx.x;
  const int c = t&255, h = t>>8, w4 = (t>>6)&3, l = t&63;
  const int r = blockIdx.x;
  const int b = r>>3, s = r&7;
  // combine (8 chunks) -> Ut, stage prev slots
  if(t < 256){
    const float* mpb = mP + b*64 + s;
    const float* lpb = lP + b*64 + s;
    float M = -1e30f;
    #pragma unroll
    for(int c8=0;c8<8;c8++) M = fmaxf(M, mpb[c8*8]);
    float wc[8]; float L = 0.f;
    #pragma unroll
    for(int c8=0;c8<8;c8++){ wc[c8] = __expf(mpb[c8*8] - M); L += lpb[c8*8]*wc[c8]; }
    float inv = 1.f/L;
    size_t base = ((size_t)b*64 + s)*256 + c;
    float u = 0.f;
    #pragma unroll
    for(int c8=0;c8<8;c8++) u += wc[c8]*aP[base + (size_t)c8*2048];
    Ut[c] = u*inv;
    Sp[c] = Sc[(size_t)r*256 + c];
  }
  __syncthreads();
  // gate GEMMs: 384 threads, (mat, col-quad), dwordx4 weight streams
  if(t < 384){
    const int mat = t/192, q4 = (t - mat*192)*4;
    const float* WT = mat ? WhhT : WihvT;
    const float* bb = mat ? bhh : bihv;
    const float* A  = mat ? Sp : Ut;
    float4 acc = *(const float4*)(bb + q4);
    const float* wp = WT + q4;
    #pragma unroll 8
    for(int d=0; d<256; ++d){
      float4 wv = *(const float4*)(wp + (size_t)d*768);
      float a = A[d];
      acc.x += a*wv.x; acc.y += a*wv.y; acc.z += a*wv.z; acc.w += a*wv.w;
    }
    *(float4*)(&Gt[mat][q4]) = acc;
  }
  __syncthreads();
  // gates + LN_ff stats (threads 0-255, waves 0-3)
  if(t < 256){
    float gir = Gt[0][c], giz = Gt[0][256+c], gin = Gt[0][512+c];
    float ghr = Gt[1][c], ghz = Gt[1][256+c], ghn = Gt[1][512+c];
    float rr = 1.f/(1.f + __expf(-(gir+ghr)));
    float zz = 1.f/(1.f + __expf(-(giz+ghz)));
    float nn = tanhf(gin + rr*ghn);
    float sp = (1.f-zz)*nn + zz*Sp[c];
    Ut[c] = sp;                      // Ut dead after gate GEMM; reuse for sp
    float s1 = sp, s2 = sp*sp;
    #pragma unroll
    for(int off=1; off<64; off<<=1){ s1 += __shfl_xor(s1,off); s2 += __shfl_xor(s2,off); }
    if(l==0){ red2[0][w4] = s1; red2[1][w4] = s2; }
  }
  __syncthreads();
  if(t < 256){
    float t1 = red2[0][0]+red2[0][1]+red2[0][2]+red2[0][3];
    float t2 = red2[1][0]+red2[1][1]+red2[1][2]+red2[1][3];
    float m = t1*(1.f/256.f);
    float var = t2*(1.f/256.f) - m*m;
    float rs = rsqrtf(var + 1e-5f);
    Row[c] = (Ut[c]-m)*rs*g_ff[c] + be_ff[c];
  }
  __syncthreads();
  // W1 + relu: 512 threads, d-split halves
  {
    const float* w1 = W1T + (size_t)h*128*256 + c;
    float acc = h ? 0.f : b1[c];
    const float* rw = &Row[h*128];
    #pragma unroll 8
    for(int d=0; d<128; ++d) acc += rw[d]*w1[(size_t)d*256];
    Hp[h][c] = acc;
  }
  __syncthreads();
  if(t < 256) Ht[c] = fmaxf(Hp[0][c]+Hp[1][c], 0.f);
  __syncthreads();
  // W2 + residual
  {
    const float* w2 = W2T + (size_t)h*128*256 + c;
    float acc = h ? 0.f : b2[c];
    const float* hw = &Ht[h*128];
    #pragma unroll 8
    for(int d=0; d<128; ++d) acc += hw[d]*w2[(size_t)d*256];
    Hp[h][c] = acc;
  }
  __syncthreads();
  if(t < 256){
    float sn = Hp[0][c]+Hp[1][c] + Ut[c];
    Sout[(size_t)r*256 + c] = sn;
    Snew[c] = sn;
  }
  if(writeQ){
    __syncthreads();
    if(t < 256){
      float sn = Snew[c];
      float s1 = sn, s2 = sn*sn;
      #pragma unroll
      for(int off=1; off<64; off<<=1){ s1 += __shfl_xor(s1,off); s2 += __shfl_xor(s2,off); }
      if(l==0){ red2[0][w4] = s1; red2[1][w4] = s2; }
    }
    __syncthreads();
    if(t < 256){
      float t1 = red2[0][0]+red2[0][1]+red2[0][2]+red2[0][3];
      float t2 = red2[1][0]+red2[1][1]+red2[1][2]+red2[1][3];
      float m = t1*(1.f/256.f);
      float var = t2*(1.f/256.f) - m*m;
      float rs = rsqrtf(var + 1e-5f);
      Lq[c] = (Snew[c]-m)*rs*g_sl[c] + be_sl[c];
    }
    __syncthreads();
    {
      const float* wq = Wqk + (size_t)h*128*256 + c;
      float acc = h ? 0.f : bqk[c];
      const float* lw = &Lq[h*128];
      #pragma unroll 8
      for(int d=0; d<128; ++d) acc += lw[d]*wq[(size_t)d*256];
      Hp[h][c] = acc;
    }
    __syncthreads();
    if(t < 256) Qq[(size_t)r*256 + c] = Hp[0][c]+Hp[1][c];
  }
}

extern "C" void kernel_launch(void* const* d_in, const int* in_sizes, int n_in,
                              void* d_out, int out_size, void* d_ws, size_t ws_size,
                              hipStream_t stream){
  const float* x    = (const float*)d_in[0];
  const float* noise= (const float*)d_in[1];
  const float* mu   = (const float*)d_in[2];
  const float* sig  = (const float*)d_in[3];
  const float* Wq   = (const float*)d_in[4];
  const float* bq   = (const float*)d_in[5];
  const float* Wk   = (const float*)d_in[6];
  // d_in[7] = bk : constant shift over n, cancels in softmax
  const float* Wv   = (const float*)d_in[8];
  const float* bv   = (const float*)d_in[9];
  const float* W_ih = (const float*)d_in[10];
  const float* b_ih = (const float*)d_in[11];
  const float* W_hh = (const float*)d_in[12];
  const float* b_hh = (const float*)d_in[13];
  const float* W1m  = (const float*)d_in[14];
  const float* b1v  = (const float*)d_in[15];
  const float* W2m  = (const float*)d_in[16];
  const float* b2v  = (const float*)d_in[17];
  const float* g_in = (const float*)d_in[18];
  const float* be_in= (const float*)d_in[19];
  const float* g_sl = (const float*)d_in[20];
  const float* be_sl= (const float*)d_in[21];
  const float* g_ff = (const float*)d_in[22];
  const float* be_ff= (const float*)d_in[23];

  char* p = (char*)d_ws;
  auto alloc = [&](size_t bytes)->char*{ char* q = p; p += (bytes + 255) & ~(size_t)255; return q; };
  u16*   xn    = (u16*)  alloc((size_t)BB*NN*DD*2);
  float* Wqk   = (float*)alloc(256*256*4);
  float* bqk   = (float*)alloc(256*4);
  float* Wihv  = (float*)alloc((size_t)768*256*4);
  float* WihvT = (float*)alloc((size_t)256*768*4);
  float* bihv  = (float*)alloc(768*4);
  float* WhhT  = (float*)alloc((size_t)256*768*4);
  float* W1T   = (float*)alloc(256*256*4);
  float* W2T   = (float*)alloc(256*256*4);
  float* S0    = (float*)alloc(512*256*4);
  float* S1    = (float*)alloc(512*256*4);
  float* Qq    = (float*)alloc(512*256*4);
  float* mP    = (float*)alloc(64*NCH*8*4);
  float* lP    = (float*)alloc(64*NCH*8*4);
  float* aP    = (float*)alloc((size_t)64*NCH*8*256*4);
  if((size_t)(p - (char*)d_ws) > ws_size) return;  // fail loudly

  kA<<<34306, 256, 0, stream>>>(x, g_in, be_in, xn, noise, mu, sig, S0,
                                Wq, Wk, bq, W_ih, Wv, bv, b_ih, Wqk, bqk, Wihv, bihv);
  kB<<<192, 256, 0, stream>>>(Wihv, W_hh, W1m, W2m, WihvT, WhhT, W1T, W2T,
                              S0, g_sl, be_sl, Wqk, bqk, Qq);

  float* Sin = S0;
  float* Sping[2] = { S1, S0 };
  for(int it=0; it<NITER; ++it){
    float* Sout = (it==NITER-1) ? (float*)d_out : Sping[it&1];
    k_attn<<<dim3(64, NCH, 2), 256, 0, stream>>>(Qq, xn, mP, lP, aP);
    k_post<<<512, 512, 0, stream>>>(mP, lP, aP, WihvT, bihv, WhhT, b_hh, Sin, g_ff, be_ff,
                                    W1T, b1v, W2T, b2v, g_sl, be_sl, Wqk, bqk,
                                    Sout, Qq, (it<NITER-1) ? 1 : 0);
    Sin = Sout;
  }
}